// Round 1
// baseline (21510.065 us; speedup 1.0000x reference)
//
#include <hip/hip_runtime.h>
#include <cstdint>
#include <cstddef>

static constexpr int NN = 50000;     // nodes
static constexpr int NE = 1600000;   // edges
static constexpr int NG = 64;        // graphs
static constexpr int FE = 16;        // edge feature dim
static constexpr float SLOPE = 0.2f; // leaky_relu negative slope

// ---- float -> orderable unsigned encoding for atomicMax-based segment max ----
__device__ __forceinline__ unsigned fenc(float f) {
    unsigned u = __float_as_uint(f);
    return (u & 0x80000000u) ? ~u : (u | 0x80000000u);
}
__device__ __forceinline__ float fdec(unsigned k) {
    unsigned u = (k & 0x80000000u) ? (k ^ 0x80000000u) : ~k;
    return __uint_as_float(u);
}

// ---- fused node linear: xl = h@Wl + bl, xr = h@Wr + br ----
// 16 rows per block, W staged in LDS.
template<int DIN, int DOUT>
__global__ __launch_bounds__(256) void k_node_linear(
    const float* __restrict__ h,
    const float* __restrict__ Wl, const float* __restrict__ bl,
    const float* __restrict__ Wr, const float* __restrict__ br,
    float* __restrict__ xl, float* __restrict__ xr)
{
    __shared__ float sW[2 * DIN * DOUT];
    __shared__ float sX[16 * DIN];
    const int n0 = blockIdx.x * 16;

    for (int i = threadIdx.x; i < DIN * DOUT; i += 256) {
        sW[i] = Wl[i];
        sW[DIN * DOUT + i] = Wr[i];
    }
    for (int i = threadIdx.x; i < 16 * DIN; i += 256) {
        int r = i / DIN, k = i % DIN;
        int n = n0 + r;
        sX[i] = (n < NN) ? h[(size_t)n * DIN + k] : 0.0f;
    }
    __syncthreads();

    for (int o = threadIdx.x; o < 16 * DOUT; o += 256) {
        int r = o / DOUT, d = o % DOUT;
        int n = n0 + r;
        if (n >= NN) continue;
        float accl = bl[d], accr = br[d];
        #pragma unroll 8
        for (int k = 0; k < DIN; ++k) {
            float xv = sX[r * DIN + k];
            accl = fmaf(xv, sW[k * DOUT + d], accl);
            accr = fmaf(xv, sW[DIN * DOUT + k * DOUT + d], accr);
        }
        xl[(size_t)n * DOUT + d] = accl;
        xr[(size_t)n * DOUT + d] = accr;
    }
}

// ---- per-edge attention score + segment max ----
// score_e = sum_d leaky_relu(xl[src,d] + xr[dst,d] + (ea@We)[e,d]) * att[d]
template<int D>
__global__ __launch_bounds__(256) void k_score(
    const float* __restrict__ xl, const float* __restrict__ xr,
    const float* __restrict__ ea, const int* __restrict__ ei,
    const float* __restrict__ We, const float* __restrict__ att,
    float* __restrict__ sc, unsigned* __restrict__ mx)
{
    const int e = blockIdx.x * 256 + threadIdx.x;
    if (e >= NE) return;
    const int src = ei[e];
    const int dst = ei[NE + e];

    float earr[FE];
    {
        const float4* p = (const float4*)(ea + (size_t)e * FE);
        float4 a = p[0], b = p[1], c = p[2], d4 = p[3];
        earr[0]=a.x; earr[1]=a.y; earr[2]=a.z; earr[3]=a.w;
        earr[4]=b.x; earr[5]=b.y; earr[6]=b.z; earr[7]=b.w;
        earr[8]=c.x; earr[9]=c.y; earr[10]=c.z; earr[11]=c.w;
        earr[12]=d4.x; earr[13]=d4.y; earr[14]=d4.z; earr[15]=d4.w;
    }

    const float* xls = xl + (size_t)src * D;
    const float* xrd = xr + (size_t)dst * D;

    float score = 0.0f;
    #pragma unroll 4
    for (int d0 = 0; d0 < D; d0 += 4) {
        float4 a = *(const float4*)(xls + d0);
        float4 b = *(const float4*)(xrd + d0);
        float m0 = a.x + b.x, m1 = a.y + b.y, m2 = a.z + b.z, m3 = a.w + b.w;
        #pragma unroll
        for (int k = 0; k < FE; ++k) {
            float4 w = *(const float4*)(We + k * D + d0);  // lane-uniform -> s_load
            m0 = fmaf(earr[k], w.x, m0);
            m1 = fmaf(earr[k], w.y, m1);
            m2 = fmaf(earr[k], w.z, m2);
            m3 = fmaf(earr[k], w.w, m3);
        }
        float4 t = *(const float4*)(att + d0);             // lane-uniform
        float l0 = m0 > 0.f ? m0 : SLOPE * m0;
        float l1 = m1 > 0.f ? m1 : SLOPE * m1;
        float l2 = m2 > 0.f ? m2 : SLOPE * m2;
        float l3 = m3 > 0.f ? m3 : SLOPE * m3;
        score = fmaf(l0, t.x, score);
        score = fmaf(l1, t.y, score);
        score = fmaf(l2, t.z, score);
        score = fmaf(l3, t.w, score);
    }
    sc[e] = score;
    atomicMax(mx + dst, fenc(score));
}

// ---- exp(score - max) and segment sum of denominators ----
__global__ __launch_bounds__(256) void k_expsum(
    const int* __restrict__ ei, const unsigned* __restrict__ mx,
    float* __restrict__ sc, float* __restrict__ den)
{
    const int e = blockIdx.x * 256 + threadIdx.x;
    if (e >= NE) return;
    const int dst = ei[NE + e];
    float s = sc[e];
    float m = fdec(mx[dst]);
    float ex = expf(s - m);
    sc[e] = ex;
    atomicAdd(den + dst, ex);
}

// ---- weighted scatter: out[dst] += alpha * xl[src] ----
template<int D>
__global__ __launch_bounds__(256) void k_aggregate(
    const float* __restrict__ sc, const float* __restrict__ den,
    const float* __restrict__ xl, const int* __restrict__ ei,
    float* __restrict__ hout)
{
    const int e = blockIdx.x * 256 + threadIdx.x;
    if (e >= NE) return;
    const int src = ei[e];
    const int dst = ei[NE + e];
    const float alpha = sc[e] / (den[dst] + 1e-16f);
    const float* xs = xl + (size_t)src * D;
    float* ho = hout + (size_t)dst * D;
    #pragma unroll 4
    for (int d0 = 0; d0 < D; d0 += 4) {
        float4 v = *(const float4*)(xs + d0);
        atomicAdd(ho + d0 + 0, alpha * v.x);
        atomicAdd(ho + d0 + 1, alpha * v.y);
        atomicAdd(ho + d0 + 2, alpha * v.z);
        atomicAdd(ho + d0 + 3, alpha * v.w);
    }
}

// ---- out = relu(out + bo) ----
template<int D>
__global__ __launch_bounds__(256) void k_bias_relu(
    float* __restrict__ h, const float* __restrict__ bo)
{
    const int i = blockIdx.x * 256 + threadIdx.x;
    if (i >= NN * D) return;
    const int d = i & (D - 1);
    h[i] = fmaxf(h[i] + bo[d], 0.0f);
}

// ---- global mean pool (sum via atomics; divide in head) ----
__global__ __launch_bounds__(128) void k_pool(
    const float* __restrict__ h, const int* __restrict__ batch,
    float* __restrict__ pooled, float* __restrict__ cnt)
{
    const int n = blockIdx.x;
    const int d = threadIdx.x;
    if (n >= NN) return;
    const int b = batch[n];
    atomicAdd(pooled + b * 128 + d, h[(size_t)n * 128 + d]);
    if (d == 0) atomicAdd(cnt + b, 1.0f);
}

// ---- dueling heads ----
__global__ __launch_bounds__(128) void k_head(
    const float* __restrict__ pooled, const float* __restrict__ cnt,
    const float* __restrict__ Wv1, const float* __restrict__ bv1,
    const float* __restrict__ Wv2, const float* __restrict__ bv2,
    const float* __restrict__ Wa1, const float* __restrict__ ba1,
    const float* __restrict__ Wa2, const float* __restrict__ ba2,
    float* __restrict__ out)
{
    __shared__ float pr[128];
    __shared__ float hv[64];
    __shared__ float ha[64];
    __shared__ float sA[10];
    __shared__ float sVM[2];
    const int g = blockIdx.x;
    const int t = threadIdx.x;

    const float inv = 1.0f / fmaxf(cnt[g], 1.0f);
    pr[t] = pooled[g * 128 + t] * inv;
    __syncthreads();

    if (t < 64) {
        float sv = bv1[t], sa = ba1[t];
        #pragma unroll 8
        for (int k = 0; k < 128; ++k) {
            float p = pr[k];
            sv = fmaf(p, Wv1[k * 64 + t], sv);
            sa = fmaf(p, Wa1[k * 64 + t], sa);
        }
        hv[t] = fmaxf(sv, 0.0f);
        ha[t] = fmaxf(sa, 0.0f);
    }
    __syncthreads();

    if (t < 10) {
        float av = ba2[t];
        #pragma unroll
        for (int j = 0; j < 64; ++j) av = fmaf(ha[j], Wa2[j * 10 + t], av);
        sA[t] = av;
    }
    if (t == 64) {
        float v = bv2[0];
        #pragma unroll
        for (int j = 0; j < 64; ++j) v = fmaf(hv[j], Wv2[j], v);
        sVM[0] = v;
    }
    __syncthreads();

    if (t == 0) {
        float s = 0.0f;
        #pragma unroll
        for (int j = 0; j < 10; ++j) s += sA[j];
        sVM[1] = s * 0.1f;
    }
    __syncthreads();

    if (t < 10) out[g * 10 + t] = sVM[0] + sA[t] - sVM[1];
}

extern "C" void kernel_launch(void* const* d_in, const int* in_sizes, int n_in,
                              void* d_out, int out_size, void* d_ws, size_t ws_size,
                              hipStream_t stream)
{
    const float* x     = (const float*)d_in[0];
    const float* ea    = (const float*)d_in[1];
    const int*   ei    = (const int*)d_in[2];   // [2*E], row0 = src, row1 = dst
    const int*   batch = (const int*)d_in[3];

    // workspace layout (floats)
    float* ws = (float*)d_ws;
    float*    xl     = ws;                              // N*128
    float*    xr     = xl + (size_t)NN * 128;           // N*128
    float*    hA     = xr + (size_t)NN * 128;           // N*128
    float*    hB     = hA + (size_t)NN * 128;           // N*128
    float*    sc     = hB + (size_t)NN * 128;           // E (scores, then exp)
    unsigned* mx     = (unsigned*)(sc + (size_t)NE);    // N
    float*    den    = (float*)(mx + NN);               // N
    float*    pooled = den + NN;                        // G*128
    float*    cnt    = pooled + (size_t)NG * 128;       // G

    const int EB = (NE + 255) / 256;

#define LAYER(DIN, DOUT, HIN, HOUT, B)                                                   \
    do {                                                                                 \
        hipMemsetAsync(mx, 0, NN * sizeof(unsigned), stream);                            \
        hipMemsetAsync(den, 0, NN * sizeof(float), stream);                              \
        hipMemsetAsync(HOUT, 0, (size_t)NN * (DOUT) * sizeof(float), stream);            \
        k_node_linear<DIN, DOUT><<<dim3((NN + 15) / 16), dim3(256), 0, stream>>>(        \
            HIN, (const float*)d_in[B], (const float*)d_in[(B) + 1],                     \
            (const float*)d_in[(B) + 2], (const float*)d_in[(B) + 3], xl, xr);           \
        k_score<DOUT><<<dim3(EB), dim3(256), 0, stream>>>(                               \
            xl, xr, ea, ei, (const float*)d_in[(B) + 4],                                 \
            (const float*)d_in[(B) + 5], sc, mx);                                        \
        k_expsum<<<dim3(EB), dim3(256), 0, stream>>>(ei, mx, sc, den);                   \
        k_aggregate<DOUT><<<dim3(EB), dim3(256), 0, stream>>>(sc, den, xl, ei, HOUT);    \
        k_bias_relu<DOUT><<<dim3((NN * (DOUT) + 255) / 256), dim3(256), 0, stream>>>(    \
            HOUT, (const float*)d_in[(B) + 6]);                                          \
    } while (0)

    LAYER(128, 32, x,  hA, 4);    // layer 1: 128 -> 32
    LAYER(32,  64, hA, hB, 11);   // layer 2: 32  -> 64
    LAYER(64, 128, hB, hA, 18);   // layer 3: 64  -> 128

#undef LAYER

    hipMemsetAsync(pooled, 0, NG * 128 * sizeof(float), stream);
    hipMemsetAsync(cnt, 0, NG * sizeof(float), stream);
    k_pool<<<dim3(NN), dim3(128), 0, stream>>>(hA, batch, pooled, cnt);
    k_head<<<dim3(NG), dim3(128), 0, stream>>>(
        pooled, cnt,
        (const float*)d_in[25], (const float*)d_in[26],
        (const float*)d_in[27], (const float*)d_in[28],
        (const float*)d_in[29], (const float*)d_in[30],
        (const float*)d_in[31], (const float*)d_in[32],
        (float*)d_out);
}

// Round 2
// 2669.626 us; speedup vs baseline: 8.0573x; 8.0573x over previous
//
#include <hip/hip_runtime.h>
#include <cstdint>
#include <cstddef>

static constexpr int NN = 50000;     // nodes
static constexpr int NE = 1600000;   // edges
static constexpr int NG = 64;        // graphs
static constexpr int FE = 16;        // edge feature dim
static constexpr float SLOPE = 0.2f; // leaky_relu negative slope

// ---- fused node linear: xl = h@Wl + bl, xr = h@Wr + br ----
template<int DIN, int DOUT>
__global__ __launch_bounds__(256) void k_node_linear(
    const float* __restrict__ h,
    const float* __restrict__ Wl, const float* __restrict__ bl,
    const float* __restrict__ Wr, const float* __restrict__ br,
    float* __restrict__ xl, float* __restrict__ xr)
{
    __shared__ float sW[2 * DIN * DOUT];
    __shared__ float sX[16 * DIN];
    const int n0 = blockIdx.x * 16;

    for (int i = threadIdx.x; i < DIN * DOUT; i += 256) {
        sW[i] = Wl[i];
        sW[DIN * DOUT + i] = Wr[i];
    }
    for (int i = threadIdx.x; i < 16 * DIN; i += 256) {
        int r = i / DIN, k = i % DIN;
        int n = n0 + r;
        sX[i] = (n < NN) ? h[(size_t)n * DIN + k] : 0.0f;
    }
    __syncthreads();

    for (int o = threadIdx.x; o < 16 * DOUT; o += 256) {
        int r = o / DOUT, d = o % DOUT;
        int n = n0 + r;
        if (n >= NN) continue;
        float accl = bl[d], accr = br[d];
        #pragma unroll 8
        for (int k = 0; k < DIN; ++k) {
            float xv = sX[r * DIN + k];
            accl = fmaf(xv, sW[k * DOUT + d], accl);
            accr = fmaf(xv, sW[DIN * DOUT + k * DOUT + d], accr);
        }
        xl[(size_t)n * DOUT + d] = accl;
        xr[(size_t)n * DOUT + d] = accr;
    }
}

// ---- per-edge attention score (no atomics) ----
template<int D>
__global__ __launch_bounds__(256) void k_score(
    const float* __restrict__ xl, const float* __restrict__ xr,
    const float* __restrict__ ea, const int* __restrict__ ei,
    const float* __restrict__ We, const float* __restrict__ att,
    float* __restrict__ sc)
{
    const int e = blockIdx.x * 256 + threadIdx.x;
    if (e >= NE) return;
    const int src = ei[e];
    const int dst = ei[NE + e];

    float earr[FE];
    {
        const float4* p = (const float4*)(ea + (size_t)e * FE);
        float4 a = p[0], b = p[1], c = p[2], d4 = p[3];
        earr[0]=a.x; earr[1]=a.y; earr[2]=a.z; earr[3]=a.w;
        earr[4]=b.x; earr[5]=b.y; earr[6]=b.z; earr[7]=b.w;
        earr[8]=c.x; earr[9]=c.y; earr[10]=c.z; earr[11]=c.w;
        earr[12]=d4.x; earr[13]=d4.y; earr[14]=d4.z; earr[15]=d4.w;
    }

    const float* xls = xl + (size_t)src * D;
    const float* xrd = xr + (size_t)dst * D;

    float score = 0.0f;
    #pragma unroll 4
    for (int d0 = 0; d0 < D; d0 += 4) {
        float4 a = *(const float4*)(xls + d0);
        float4 b = *(const float4*)(xrd + d0);
        float m0 = a.x + b.x, m1 = a.y + b.y, m2 = a.z + b.z, m3 = a.w + b.w;
        #pragma unroll
        for (int k = 0; k < FE; ++k) {
            float4 w = *(const float4*)(We + k * D + d0);  // lane-uniform
            m0 = fmaf(earr[k], w.x, m0);
            m1 = fmaf(earr[k], w.y, m1);
            m2 = fmaf(earr[k], w.z, m2);
            m3 = fmaf(earr[k], w.w, m3);
        }
        float4 t = *(const float4*)(att + d0);             // lane-uniform
        float l0 = m0 > 0.f ? m0 : SLOPE * m0;
        float l1 = m1 > 0.f ? m1 : SLOPE * m1;
        float l2 = m2 > 0.f ? m2 : SLOPE * m2;
        float l3 = m3 > 0.f ? m3 : SLOPE * m3;
        score = fmaf(l0, t.x, score);
        score = fmaf(l1, t.y, score);
        score = fmaf(l2, t.z, score);
        score = fmaf(l3, t.w, score);
    }
    sc[e] = score;
}

// ---- CSR build: count / scan / fill ----
__global__ __launch_bounds__(256) void k_count(
    const int* __restrict__ ei, int* __restrict__ cnt)
{
    const int e = blockIdx.x * 256 + threadIdx.x;
    if (e >= NE) return;
    atomicAdd(cnt + ei[NE + e], 1);
}

__global__ __launch_bounds__(1024) void k_scan(
    const int* __restrict__ cnt, int* __restrict__ rowptr)
{
    __shared__ int part[1024];
    const int T = 1024;
    const int C = (NN + T - 1) / T;   // 49
    const int t = threadIdx.x;
    const int base = t * C;
    int s = 0;
    for (int i = 0; i < C; ++i) {
        int idx = base + i;
        if (idx < NN) s += cnt[idx];
    }
    part[t] = s;
    __syncthreads();
    for (int off = 1; off < T; off <<= 1) {
        int v = 0;
        if (t >= off) v = part[t - off];
        __syncthreads();
        if (t >= off) part[t] += v;
        __syncthreads();
    }
    int run = (t == 0) ? 0 : part[t - 1];
    for (int i = 0; i < C; ++i) {
        int idx = base + i;
        if (idx < NN) { rowptr[idx] = run; run += cnt[idx]; }
    }
    if (t == T - 1) rowptr[NN] = run;
}

__global__ __launch_bounds__(256) void k_fill(
    const int* __restrict__ ei, const int* __restrict__ rowptr,
    int* __restrict__ woff, int* __restrict__ eids)
{
    const int e = blockIdx.x * 256 + threadIdx.x;
    if (e >= NE) return;
    const int dst = ei[NE + e];
    const int pos = atomicAdd(woff + dst, 1);
    eids[rowptr[dst] + pos] = e;
}

// ---- per-dst softmax + weighted aggregate + bias + relu ----
// One 128-thread block per destination node. Thread t owns output dim t (t<D).
template<int D>
__global__ __launch_bounds__(128) void k_dst_agg(
    const int* __restrict__ rowptr, const int* __restrict__ eids,
    const int* __restrict__ ei,     // src row of edge_index
    const float* __restrict__ sc, const float* __restrict__ xl,
    const float* __restrict__ bo, float* __restrict__ hout)
{
    const int n = blockIdx.x;
    const int t = threadIdx.x;
    const int p0 = rowptr[n], p1 = rowptr[n + 1];

    __shared__ float red[128];
    __shared__ float s_a[128];
    __shared__ int   s_s[128];

    // --- pass 1a: segment max ---
    float mx = -3.4e38f;
    for (int p = p0 + t; p < p1; p += 128) mx = fmaxf(mx, sc[eids[p]]);
    red[t] = mx;
    __syncthreads();
    #pragma unroll
    for (int o = 64; o > 0; o >>= 1) {
        if (t < o) red[t] = fmaxf(red[t], red[t + o]);
        __syncthreads();
    }
    mx = red[0];
    __syncthreads();

    // --- pass 1b: denominator ---
    float dn = 0.0f;
    for (int p = p0 + t; p < p1; p += 128) dn += expf(sc[eids[p]] - mx);
    red[t] = dn;
    __syncthreads();
    #pragma unroll
    for (int o = 64; o > 0; o >>= 1) {
        if (t < o) red[t] += red[t + o];
        __syncthreads();
    }
    const float inv_den = 1.0f / (red[0] + 1e-16f);
    __syncthreads();

    // --- pass 2: alpha * gather-accumulate ---
    float acc = 0.0f;
    for (int base = p0; base < p1; base += 128) {
        const int chunk = min(128, p1 - base);
        if (t < chunk) {
            const int e = eids[base + t];
            s_a[t] = expf(sc[e] - mx) * inv_den;
            s_s[t] = ei[e];   // src node
        }
        __syncthreads();
        if (t < D) {
            for (int j = 0; j < chunk; ++j)
                acc = fmaf(s_a[j], xl[(size_t)s_s[j] * D + t], acc);
        }
        __syncthreads();
    }

    if (t < D) hout[(size_t)n * D + t] = fmaxf(acc + bo[t], 0.0f);
}

// ---- global mean pool (sum via atomics; divide in head) ----
__global__ __launch_bounds__(128) void k_pool(
    const float* __restrict__ h, const int* __restrict__ batch,
    float* __restrict__ pooled, float* __restrict__ cnt)
{
    const int n = blockIdx.x;
    const int d = threadIdx.x;
    if (n >= NN) return;
    const int b = batch[n];
    atomicAdd(pooled + b * 128 + d, h[(size_t)n * 128 + d]);
    if (d == 0) atomicAdd(cnt + b, 1.0f);
}

// ---- dueling heads ----
__global__ __launch_bounds__(128) void k_head(
    const float* __restrict__ pooled, const float* __restrict__ cnt,
    const float* __restrict__ Wv1, const float* __restrict__ bv1,
    const float* __restrict__ Wv2, const float* __restrict__ bv2,
    const float* __restrict__ Wa1, const float* __restrict__ ba1,
    const float* __restrict__ Wa2, const float* __restrict__ ba2,
    float* __restrict__ out)
{
    __shared__ float pr[128];
    __shared__ float hv[64];
    __shared__ float ha[64];
    __shared__ float sA[10];
    __shared__ float sVM[2];
    const int g = blockIdx.x;
    const int t = threadIdx.x;

    const float inv = 1.0f / fmaxf(cnt[g], 1.0f);
    pr[t] = pooled[g * 128 + t] * inv;
    __syncthreads();

    if (t < 64) {
        float sv = bv1[t], sa = ba1[t];
        #pragma unroll 8
        for (int k = 0; k < 128; ++k) {
            float p = pr[k];
            sv = fmaf(p, Wv1[k * 64 + t], sv);
            sa = fmaf(p, Wa1[k * 64 + t], sa);
        }
        hv[t] = fmaxf(sv, 0.0f);
        ha[t] = fmaxf(sa, 0.0f);
    }
    __syncthreads();

    if (t < 10) {
        float av = ba2[t];
        #pragma unroll
        for (int j = 0; j < 64; ++j) av = fmaf(ha[j], Wa2[j * 10 + t], av);
        sA[t] = av;
    }
    if (t == 64) {
        float v = bv2[0];
        #pragma unroll
        for (int j = 0; j < 64; ++j) v = fmaf(hv[j], Wv2[j], v);
        sVM[0] = v;
    }
    __syncthreads();

    if (t == 0) {
        float s = 0.0f;
        #pragma unroll
        for (int j = 0; j < 10; ++j) s += sA[j];
        sVM[1] = s * 0.1f;
    }
    __syncthreads();

    if (t < 10) out[g * 10 + t] = sVM[0] + sA[t] - sVM[1];
}

extern "C" void kernel_launch(void* const* d_in, const int* in_sizes, int n_in,
                              void* d_out, int out_size, void* d_ws, size_t ws_size,
                              hipStream_t stream)
{
    const float* x     = (const float*)d_in[0];
    const float* ea    = (const float*)d_in[1];
    const int*   ei    = (const int*)d_in[2];   // [2*E], row0 = src, row1 = dst
    const int*   batch = (const int*)d_in[3];

    // workspace layout
    float* ws = (float*)d_ws;
    float* xl     = ws;                              // N*128
    float* xr     = xl + (size_t)NN * 128;           // N*128
    float* hA     = xr + (size_t)NN * 128;           // N*128
    float* hB     = hA + (size_t)NN * 128;           // N*128
    float* sc     = hB + (size_t)NN * 128;           // E
    float* pooled = sc + (size_t)NE;                 // G*128
    float* cntp   = pooled + (size_t)NG * 128;       // G
    int*   rowptr = (int*)(cntp + NG);               // NN+1
    int*   cnt    = rowptr + (NN + 1);               // NN
    int*   woff   = cnt + NN;                        // NN
    int*   eids   = woff + NN;                       // NE

    const int EB = (NE + 255) / 256;

    // ---- CSR by destination (shared across all 3 layers) ----
    hipMemsetAsync(cnt, 0, NN * sizeof(int), stream);
    hipMemsetAsync(woff, 0, NN * sizeof(int), stream);
    k_count<<<dim3(EB), dim3(256), 0, stream>>>(ei, cnt);
    k_scan<<<dim3(1), dim3(1024), 0, stream>>>(cnt, rowptr);
    k_fill<<<dim3(EB), dim3(256), 0, stream>>>(ei, rowptr, woff, eids);

#define LAYER(DIN, DOUT, HIN, HOUT, B)                                                   \
    do {                                                                                 \
        k_node_linear<DIN, DOUT><<<dim3((NN + 15) / 16), dim3(256), 0, stream>>>(        \
            HIN, (const float*)d_in[B], (const float*)d_in[(B) + 1],                     \
            (const float*)d_in[(B) + 2], (const float*)d_in[(B) + 3], xl, xr);           \
        k_score<DOUT><<<dim3(EB), dim3(256), 0, stream>>>(                               \
            xl, xr, ea, ei, (const float*)d_in[(B) + 4],                                 \
            (const float*)d_in[(B) + 5], sc);                                            \
        k_dst_agg<DOUT><<<dim3(NN), dim3(128), 0, stream>>>(                             \
            rowptr, eids, ei, sc, xl, (const float*)d_in[(B) + 6], HOUT);                \
    } while (0)

    LAYER(128, 32, x,  hA, 4);    // layer 1: 128 -> 32
    LAYER(32,  64, hA, hB, 11);   // layer 2: 32  -> 64
    LAYER(64, 128, hB, hA, 18);   // layer 3: 64  -> 128

#undef LAYER

    hipMemsetAsync(pooled, 0, NG * 128 * sizeof(float), stream);
    hipMemsetAsync(cntp, 0, NG * sizeof(float), stream);
    k_pool<<<dim3(NN), dim3(128), 0, stream>>>(hA, batch, pooled, cntp);
    k_head<<<dim3(NG), dim3(128), 0, stream>>>(
        pooled, cntp,
        (const float*)d_in[25], (const float*)d_in[26],
        (const float*)d_in[27], (const float*)d_in[28],
        (const float*)d_in[29], (const float*)d_in[30],
        (const float*)d_in[31], (const float*)d_in[32],
        (float*)d_out);
}

// Round 3
// 1823.746 us; speedup vs baseline: 11.7944x; 1.4638x over previous
//
#include <hip/hip_runtime.h>
#include <cstdint>
#include <cstddef>

static constexpr int NN = 50000;     // nodes
static constexpr int NE = 1600000;   // edges
static constexpr int NG = 64;        // graphs
static constexpr int FE = 16;        // edge feature dim
static constexpr float SLOPE = 0.2f; // leaky_relu negative slope

// ---- fused node linear: xl = h@Wl + bl, xr = h@Wr + br ----
template<int DIN, int DOUT>
__global__ __launch_bounds__(256) void k_node_linear(
    const float* __restrict__ h,
    const float* __restrict__ Wl, const float* __restrict__ bl,
    const float* __restrict__ Wr, const float* __restrict__ br,
    float* __restrict__ xl, float* __restrict__ xr)
{
    __shared__ float sW[2 * DIN * DOUT];
    __shared__ float sX[16 * DIN];
    const int n0 = blockIdx.x * 16;

    for (int i = threadIdx.x; i < DIN * DOUT; i += 256) {
        sW[i] = Wl[i];
        sW[DIN * DOUT + i] = Wr[i];
    }
    for (int i = threadIdx.x; i < 16 * DIN; i += 256) {
        int r = i / DIN, k = i % DIN;
        int n = n0 + r;
        sX[i] = (n < NN) ? h[(size_t)n * DIN + k] : 0.0f;
    }
    __syncthreads();

    for (int o = threadIdx.x; o < 16 * DOUT; o += 256) {
        int r = o / DOUT, d = o % DOUT;
        int n = n0 + r;
        if (n >= NN) continue;
        float accl = bl[d], accr = br[d];
        #pragma unroll 8
        for (int k = 0; k < DIN; ++k) {
            float xv = sX[r * DIN + k];
            accl = fmaf(xv, sW[k * DOUT + d], accl);
            accr = fmaf(xv, sW[DIN * DOUT + k * DOUT + d], accr);
        }
        xl[(size_t)n * DOUT + d] = accl;
        xr[(size_t)n * DOUT + d] = accr;
    }
}

// ---- CSR build: count / scan / fill (+ permuted src ids) ----
__global__ __launch_bounds__(256) void k_count(
    const int* __restrict__ ei, int* __restrict__ cnt)
{
    const int e = blockIdx.x * 256 + threadIdx.x;
    if (e >= NE) return;
    atomicAdd(cnt + ei[NE + e], 1);
}

__global__ __launch_bounds__(1024) void k_scan(
    const int* __restrict__ cnt, int* __restrict__ rowptr)
{
    __shared__ int part[1024];
    const int T = 1024;
    const int C = (NN + T - 1) / T;
    const int t = threadIdx.x;
    const int base = t * C;
    int s = 0;
    for (int i = 0; i < C; ++i) {
        int idx = base + i;
        if (idx < NN) s += cnt[idx];
    }
    part[t] = s;
    __syncthreads();
    for (int off = 1; off < T; off <<= 1) {
        int v = 0;
        if (t >= off) v = part[t - off];
        __syncthreads();
        if (t >= off) part[t] += v;
        __syncthreads();
    }
    int run = (t == 0) ? 0 : part[t - 1];
    for (int i = 0; i < C; ++i) {
        int idx = base + i;
        if (idx < NN) { rowptr[idx] = run; run += cnt[idx]; }
    }
    if (t == T - 1) rowptr[NN] = run;
}

__global__ __launch_bounds__(256) void k_fill(
    const int* __restrict__ ei, const int* __restrict__ rowptr,
    int* __restrict__ woff, int* __restrict__ eids, int* __restrict__ esrc)
{
    const int e = blockIdx.x * 256 + threadIdx.x;
    if (e >= NE) return;
    const int dst = ei[NE + e];
    const int pos = rowptr[dst] + atomicAdd(woff + dst, 1);
    eids[pos] = e;
    esrc[pos] = ei[e];
}

// ---- fused GATv2: score + online softmax + aggregate + bias + relu ----
// One 128-thread block per destination node.
template<int D>
__global__ __launch_bounds__(128) void k_gat_fused(
    const int* __restrict__ rowptr, const int* __restrict__ eids,
    const int* __restrict__ esrc, const float* __restrict__ ea,
    const float* __restrict__ xl, const float* __restrict__ xr,
    const float* __restrict__ We, const float* __restrict__ att,
    const float* __restrict__ bo, float* __restrict__ hout)
{
    constexpr int THREADS = 128;
    constexpr int CE = 32;           // edges per chunk
    constexpr int R = THREADS / D;   // row-groups in accumulate phase
    constexpr int QD = D / 4;        // dims per scoring lane

    __shared__ float sWe[FE * D];
    __shared__ float sAtt[D];
    __shared__ float sXr[D];
    __shared__ float sS[CE];
    __shared__ float sWt[CE];
    __shared__ int   sSrc[CE];
    __shared__ float sRed[THREADS];
    __shared__ float sL[R];

    const int n = blockIdx.x;
    const int t = threadIdx.x;

    for (int i = t; i < FE * D; i += THREADS) sWe[i] = We[i];
    for (int i = t; i < D; i += THREADS) { sAtt[i] = att[i]; sXr[i] = xr[(size_t)n * D + i]; }
    __syncthreads();

    const int p0 = rowptr[n], p1 = rowptr[n + 1];
    const int d = t % D;             // owned output dim
    const int g = t / D;             // edge sub-group
    const int j4 = t >> 2, q = t & 3;
    const int qoff = q * QD;

    float m = -3.4e38f, l = 0.f, acc = 0.f;

    for (int base = p0; base < p1; base += CE) {
        const int chunk = min(CE, p1 - base);

        // --- score phase: 4 lanes per edge ---
        if (j4 < chunk) {
            const int p = base + j4;
            const int s = esrc[p];
            const int e = eids[p];
            if (q == 0) sSrc[j4] = s;
            const float4* eap = (const float4*)(ea + (size_t)e * FE);
            float4 e0 = eap[0], e1 = eap[1], e2 = eap[2], e3 = eap[3];
            float ek[FE] = {e0.x,e0.y,e0.z,e0.w, e1.x,e1.y,e1.z,e1.w,
                            e2.x,e2.y,e2.z,e2.w, e3.x,e3.y,e3.z,e3.w};
            const float* xlr = xl + (size_t)s * D + qoff;
            float sv = 0.f;
            #pragma unroll
            for (int i0 = 0; i0 < QD; i0 += 4) {
                float4 a  = *(const float4*)(xlr + i0);
                float4 b  = *(const float4*)(sXr + qoff + i0);
                float4 at = *(const float4*)(sAtt + qoff + i0);
                float m0 = a.x + b.x, m1 = a.y + b.y, m2 = a.z + b.z, m3 = a.w + b.w;
                #pragma unroll
                for (int k = 0; k < FE; ++k) {
                    float4 w = *(const float4*)(sWe + k * D + qoff + i0);
                    m0 = fmaf(ek[k], w.x, m0);
                    m1 = fmaf(ek[k], w.y, m1);
                    m2 = fmaf(ek[k], w.z, m2);
                    m3 = fmaf(ek[k], w.w, m3);
                }
                m0 = m0 > 0.f ? m0 : SLOPE * m0;
                m1 = m1 > 0.f ? m1 : SLOPE * m1;
                m2 = m2 > 0.f ? m2 : SLOPE * m2;
                m3 = m3 > 0.f ? m3 : SLOPE * m3;
                sv = fmaf(m0, at.x, sv);
                sv = fmaf(m1, at.y, sv);
                sv = fmaf(m2, at.z, sv);
                sv = fmaf(m3, at.w, sv);
            }
            sv += __shfl_xor(sv, 1);
            sv += __shfl_xor(sv, 2);
            if (q == 0) sS[j4] = sv;
        }
        __syncthreads();

        // --- online softmax update ---
        float cmax = -3.4e38f;
        for (int j = 0; j < chunk; ++j) cmax = fmaxf(cmax, sS[j]);
        const float mnew = fmaxf(m, cmax);
        const float r = __expf(m - mnew);
        acc *= r; l *= r; m = mnew;
        if (t < chunk) sWt[t] = __expf(sS[t] - mnew);
        __syncthreads();

        // --- accumulate phase: dim-per-thread, coalesced row reads ---
        for (int j = g; j < chunk; j += R) {
            const float w = sWt[j];
            l += w;
            acc = fmaf(w, xl[(size_t)sSrc[j] * D + d], acc);
        }
        __syncthreads();
    }

    if constexpr (R > 1) {
        sRed[t] = acc;
        if (d == 0) sL[g] = l;
        __syncthreads();
        if (t < D) {
            float a = sRed[t], lt = sL[0];
            #pragma unroll
            for (int gg = 1; gg < R; ++gg) { a += sRed[gg * D + t]; lt += sL[gg]; }
            hout[(size_t)n * D + t] = fmaxf(a / (lt + 1e-16f) + bo[t], 0.f);
        }
    } else {
        hout[(size_t)n * D + t] = fmaxf(acc / (l + 1e-16f) + bo[t], 0.f);
    }
}

// ---- global mean pool (sum via atomics; divide in head) ----
__global__ __launch_bounds__(128) void k_pool(
    const float* __restrict__ h, const int* __restrict__ batch,
    float* __restrict__ pooled, float* __restrict__ cnt)
{
    const int n = blockIdx.x;
    const int d = threadIdx.x;
    if (n >= NN) return;
    const int b = batch[n];
    atomicAdd(pooled + b * 128 + d, h[(size_t)n * 128 + d]);
    if (d == 0) atomicAdd(cnt + b, 1.0f);
}

// ---- dueling heads ----
__global__ __launch_bounds__(128) void k_head(
    const float* __restrict__ pooled, const float* __restrict__ cnt,
    const float* __restrict__ Wv1, const float* __restrict__ bv1,
    const float* __restrict__ Wv2, const float* __restrict__ bv2,
    const float* __restrict__ Wa1, const float* __restrict__ ba1,
    const float* __restrict__ Wa2, const float* __restrict__ ba2,
    float* __restrict__ out)
{
    __shared__ float pr[128];
    __shared__ float hv[64];
    __shared__ float ha[64];
    __shared__ float sA[10];
    __shared__ float sVM[2];
    const int g = blockIdx.x;
    const int t = threadIdx.x;

    const float inv = 1.0f / fmaxf(cnt[g], 1.0f);
    pr[t] = pooled[g * 128 + t] * inv;
    __syncthreads();

    if (t < 64) {
        float sv = bv1[t], sa = ba1[t];
        #pragma unroll 8
        for (int k = 0; k < 128; ++k) {
            float p = pr[k];
            sv = fmaf(p, Wv1[k * 64 + t], sv);
            sa = fmaf(p, Wa1[k * 64 + t], sa);
        }
        hv[t] = fmaxf(sv, 0.0f);
        ha[t] = fmaxf(sa, 0.0f);
    }
    __syncthreads();

    if (t < 10) {
        float av = ba2[t];
        #pragma unroll
        for (int j = 0; j < 64; ++j) av = fmaf(ha[j], Wa2[j * 10 + t], av);
        sA[t] = av;
    }
    if (t == 64) {
        float v = bv2[0];
        #pragma unroll
        for (int j = 0; j < 64; ++j) v = fmaf(hv[j], Wv2[j], v);
        sVM[0] = v;
    }
    __syncthreads();

    if (t == 0) {
        float s = 0.0f;
        #pragma unroll
        for (int j = 0; j < 10; ++j) s += sA[j];
        sVM[1] = s * 0.1f;
    }
    __syncthreads();

    if (t < 10) out[g * 10 + t] = sVM[0] + sA[t] - sVM[1];
}

extern "C" void kernel_launch(void* const* d_in, const int* in_sizes, int n_in,
                              void* d_out, int out_size, void* d_ws, size_t ws_size,
                              hipStream_t stream)
{
    const float* x     = (const float*)d_in[0];
    const float* ea    = (const float*)d_in[1];
    const int*   ei    = (const int*)d_in[2];   // [2*E], row0 = src, row1 = dst
    const int*   batch = (const int*)d_in[3];

    // workspace layout
    float* ws = (float*)d_ws;
    float* xl     = ws;                              // N*128
    float* xr     = xl + (size_t)NN * 128;           // N*128
    float* hA     = xr + (size_t)NN * 128;           // N*128
    float* hB     = hA + (size_t)NN * 128;           // N*128
    float* pooled = hB + (size_t)NN * 128;           // G*128
    float* cntp   = pooled + (size_t)NG * 128;       // G
    int*   rowptr = (int*)(cntp + NG);               // NN+1
    int*   cnt    = rowptr + (NN + 1);               // NN
    int*   woff   = cnt + NN;                        // NN
    int*   eids   = woff + NN;                       // NE
    int*   esrc   = eids + NE;                       // NE

    const int EB = (NE + 255) / 256;

    // ---- CSR by destination (shared across all 3 layers) ----
    hipMemsetAsync(cnt, 0, NN * sizeof(int), stream);
    hipMemsetAsync(woff, 0, NN * sizeof(int), stream);
    k_count<<<dim3(EB), dim3(256), 0, stream>>>(ei, cnt);
    k_scan<<<dim3(1), dim3(1024), 0, stream>>>(cnt, rowptr);
    k_fill<<<dim3(EB), dim3(256), 0, stream>>>(ei, rowptr, woff, eids, esrc);

#define LAYER(DIN, DOUT, HIN, HOUT, B)                                                   \
    do {                                                                                 \
        k_node_linear<DIN, DOUT><<<dim3((NN + 15) / 16), dim3(256), 0, stream>>>(        \
            HIN, (const float*)d_in[B], (const float*)d_in[(B) + 1],                     \
            (const float*)d_in[(B) + 2], (const float*)d_in[(B) + 3], xl, xr);           \
        k_gat_fused<DOUT><<<dim3(NN), dim3(128), 0, stream>>>(                           \
            rowptr, eids, esrc, ea, xl, xr, (const float*)d_in[(B) + 4],                 \
            (const float*)d_in[(B) + 5], (const float*)d_in[(B) + 6], HOUT);             \
    } while (0)

    LAYER(128, 32, x,  hA, 4);    // layer 1: 128 -> 32
    LAYER(32,  64, hA, hB, 11);   // layer 2: 32  -> 64
    LAYER(64, 128, hB, hA, 18);   // layer 3: 64  -> 128

#undef LAYER

    hipMemsetAsync(pooled, 0, NG * 128 * sizeof(float), stream);
    hipMemsetAsync(cntp, 0, NG * sizeof(float), stream);
    k_pool<<<dim3(NN), dim3(128), 0, stream>>>(hA, batch, pooled, cntp);
    k_head<<<dim3(NG), dim3(128), 0, stream>>>(
        pooled, cntp,
        (const float*)d_in[25], (const float*)d_in[26],
        (const float*)d_in[27], (const float*)d_in[28],
        (const float*)d_in[29], (const float*)d_in[30],
        (const float*)d_in[31], (const float*)d_in[32],
        (float*)d_out);
}

// Round 4
// 1395.664 us; speedup vs baseline: 15.4121x; 1.3067x over previous
//
#include <hip/hip_runtime.h>
#include <cstdint>
#include <cstddef>

static constexpr int NN = 50000;     // nodes
static constexpr int NE = 1600000;   // edges
static constexpr int NG = 64;        // graphs
static constexpr int FE = 16;        // edge feature dim
static constexpr float SLOPE = 0.2f; // leaky_relu negative slope

// ---- fused node linear: xl = h@Wl + bl, xr = h@Wr + br ----
template<int DIN, int DOUT>
__global__ __launch_bounds__(256) void k_node_linear(
    const float* __restrict__ h,
    const float* __restrict__ Wl, const float* __restrict__ bl,
    const float* __restrict__ Wr, const float* __restrict__ br,
    float* __restrict__ xl, float* __restrict__ xr)
{
    __shared__ float sW[2 * DIN * DOUT];
    __shared__ float sX[16 * DIN];
    const int n0 = blockIdx.x * 16;

    for (int i = threadIdx.x; i < DIN * DOUT; i += 256) {
        sW[i] = Wl[i];
        sW[DIN * DOUT + i] = Wr[i];
    }
    for (int i = threadIdx.x; i < 16 * DIN; i += 256) {
        int r = i / DIN, k = i % DIN;
        int n = n0 + r;
        sX[i] = (n < NN) ? h[(size_t)n * DIN + k] : 0.0f;
    }
    __syncthreads();

    for (int o = threadIdx.x; o < 16 * DOUT; o += 256) {
        int r = o / DOUT, d = o % DOUT;
        int n = n0 + r;
        if (n >= NN) continue;
        float accl = bl[d], accr = br[d];
        #pragma unroll 8
        for (int k = 0; k < DIN; ++k) {
            float xv = sX[r * DIN + k];
            accl = fmaf(xv, sW[k * DOUT + d], accl);
            accr = fmaf(xv, sW[DIN * DOUT + k * DOUT + d], accr);
        }
        xl[(size_t)n * DOUT + d] = accl;
        xr[(size_t)n * DOUT + d] = accr;
    }
}

// ---- CSR build: count / scan / fill (+ permuted src ids) ----
__global__ __launch_bounds__(256) void k_count(
    const int* __restrict__ ei, int* __restrict__ cnt)
{
    const int e = blockIdx.x * 256 + threadIdx.x;
    if (e >= NE) return;
    atomicAdd(cnt + ei[NE + e], 1);
}

__global__ __launch_bounds__(1024) void k_scan(
    const int* __restrict__ cnt, int* __restrict__ rowptr)
{
    __shared__ int part[1024];
    const int T = 1024;
    const int C = (NN + T - 1) / T;
    const int t = threadIdx.x;
    const int base = t * C;
    int s = 0;
    for (int i = 0; i < C; ++i) {
        int idx = base + i;
        if (idx < NN) s += cnt[idx];
    }
    part[t] = s;
    __syncthreads();
    for (int off = 1; off < T; off <<= 1) {
        int v = 0;
        if (t >= off) v = part[t - off];
        __syncthreads();
        if (t >= off) part[t] += v;
        __syncthreads();
    }
    int run = (t == 0) ? 0 : part[t - 1];
    for (int i = 0; i < C; ++i) {
        int idx = base + i;
        if (idx < NN) { rowptr[idx] = run; run += cnt[idx]; }
    }
    if (t == T - 1) rowptr[NN] = run;
}

__global__ __launch_bounds__(256) void k_fill(
    const int* __restrict__ ei, const int* __restrict__ rowptr,
    int* __restrict__ woff, int* __restrict__ eids, int* __restrict__ esrc)
{
    const int e = blockIdx.x * 256 + threadIdx.x;
    if (e >= NE) return;
    const int dst = ei[NE + e];
    const int pos = rowptr[dst] + atomicAdd(woff + dst, 1);
    eids[pos] = e;
    esrc[pos] = ei[e];
}

// ---- fused GATv2: score + online softmax + aggregate + bias + relu ----
// One 128-thread block per destination node.
// LDS q-blocks padded by +4 floats so the 4 scoring lanes' addresses land in
// disjoint bank quads (q-stride = QD+4 words; QD ≡ 0 mod 32 was a 4-way conflict).
template<int D>
__global__ __launch_bounds__(128) void k_gat_fused(
    const int* __restrict__ rowptr, const int* __restrict__ eids,
    const int* __restrict__ esrc, const float* __restrict__ ea,
    const float* __restrict__ xl, const float* __restrict__ xr,
    const float* __restrict__ We, const float* __restrict__ att,
    const float* __restrict__ bo, float* __restrict__ hout)
{
    constexpr int THREADS = 128;
    constexpr int CE = 32;           // edges per chunk
    constexpr int R = THREADS / D;   // row-groups in accumulate phase
    constexpr int QD = D / 4;        // dims per scoring lane
    constexpr int QP = QD + 4;       // padded q-block stride (words)
    constexpr int DP = 4 * QP;       // padded row stride (words)

    __shared__ float sWe[FE * DP];
    __shared__ float sAtt[DP];
    __shared__ float sXr[DP];
    __shared__ float sS[CE];
    __shared__ float sWt[CE];
    __shared__ int   sSrc[CE];
    __shared__ float sRed[THREADS];
    __shared__ float sL[R];

    const int n = blockIdx.x;
    const int t = threadIdx.x;

    for (int i = t; i < FE * D; i += THREADS) {
        int k = i / D, r = i % D;
        int q = r / QD, ii = r % QD;
        sWe[k * DP + q * QP + ii] = We[i];
    }
    for (int i = t; i < D; i += THREADS) {
        int q = i / QD, ii = i % QD;
        sAtt[q * QP + ii] = att[i];
        sXr[q * QP + ii] = xr[(size_t)n * D + i];
    }
    __syncthreads();

    const int p0 = rowptr[n], p1 = rowptr[n + 1];
    const int d = t % D;             // owned output dim
    const int g = t / D;             // edge sub-group
    const int j4 = t >> 2, q = t & 3;
    const int qbase = q * QP;

    float m = -3.4e38f, l = 0.f, acc = 0.f;

    for (int base = p0; base < p1; base += CE) {
        const int chunk = min(CE, p1 - base);

        // --- score phase: 4 lanes per edge ---
        if (j4 < chunk) {
            const int p = base + j4;
            const int s = esrc[p];
            const int e = eids[p];
            if (q == 0) sSrc[j4] = s;
            const float4* eap = (const float4*)(ea + (size_t)e * FE);
            float4 e0 = eap[0], e1 = eap[1], e2 = eap[2], e3 = eap[3];
            float ek[FE] = {e0.x,e0.y,e0.z,e0.w, e1.x,e1.y,e1.z,e1.w,
                            e2.x,e2.y,e2.z,e2.w, e3.x,e3.y,e3.z,e3.w};
            const float* xlr = xl + (size_t)s * D + q * QD;
            float sv = 0.f;
            #pragma unroll
            for (int i0 = 0; i0 < QD; i0 += 4) {
                float4 a  = *(const float4*)(xlr + i0);
                float4 b  = *(const float4*)(sXr + qbase + i0);
                float4 at = *(const float4*)(sAtt + qbase + i0);
                float m0 = a.x + b.x, m1 = a.y + b.y, m2 = a.z + b.z, m3 = a.w + b.w;
                #pragma unroll
                for (int k = 0; k < FE; ++k) {
                    float4 w = *(const float4*)(sWe + k * DP + qbase + i0);
                    m0 = fmaf(ek[k], w.x, m0);
                    m1 = fmaf(ek[k], w.y, m1);
                    m2 = fmaf(ek[k], w.z, m2);
                    m3 = fmaf(ek[k], w.w, m3);
                }
                m0 = m0 > 0.f ? m0 : SLOPE * m0;
                m1 = m1 > 0.f ? m1 : SLOPE * m1;
                m2 = m2 > 0.f ? m2 : SLOPE * m2;
                m3 = m3 > 0.f ? m3 : SLOPE * m3;
                sv = fmaf(m0, at.x, sv);
                sv = fmaf(m1, at.y, sv);
                sv = fmaf(m2, at.z, sv);
                sv = fmaf(m3, at.w, sv);
            }
            sv += __shfl_xor(sv, 1);
            sv += __shfl_xor(sv, 2);
            if (q == 0) sS[j4] = sv;
        }
        __syncthreads();

        // --- online softmax update ---
        float cmax = -3.4e38f;
        for (int j = 0; j < chunk; ++j) cmax = fmaxf(cmax, sS[j]);
        const float mnew = fmaxf(m, cmax);
        const float r = __expf(m - mnew);
        acc *= r; l *= r; m = mnew;
        if (t < chunk) sWt[t] = __expf(sS[t] - mnew);
        __syncthreads();

        // --- accumulate phase: dim-per-thread, coalesced row reads ---
        for (int j = g; j < chunk; j += R) {
            const float w = sWt[j];
            l += w;
            acc = fmaf(w, xl[(size_t)sSrc[j] * D + d], acc);
        }
        __syncthreads();
    }

    if constexpr (R > 1) {
        sRed[t] = acc;
        if (d == 0) sL[g] = l;
        __syncthreads();
        if (t < D) {
            float a = sRed[t], lt = sL[0];
            #pragma unroll
            for (int gg = 1; gg < R; ++gg) { a += sRed[gg * D + t]; lt += sL[gg]; }
            hout[(size_t)n * D + t] = fmaxf(a / (lt + 1e-16f) + bo[t], 0.f);
        }
    } else {
        hout[(size_t)n * D + t] = fmaxf(acc / (l + 1e-16f) + bo[t], 0.f);
    }
}

// ---- global mean pool: run-length reduction over sorted batch ----
// Block b scans a contiguous node range; one atomicAdd per graph-run.
__global__ __launch_bounds__(128) void k_pool(
    const float* __restrict__ h, const int* __restrict__ batch,
    float* __restrict__ pooled, float* __restrict__ cnt)
{
    constexpr int BLOCKS = 512;
    constexpr int CH = (NN + BLOCKS - 1) / BLOCKS;
    const int t = threadIdx.x;
    const int n0 = blockIdx.x * CH;
    const int n1 = min(NN, n0 + CH);
    if (n0 >= n1) return;

    int g = batch[n0];
    float acc = 0.f, c = 0.f;
    for (int n = n0; n < n1; ++n) {
        const int bg = batch[n];
        if (bg != g) {
            atomicAdd(pooled + g * 128 + t, acc);
            if (t == 0) atomicAdd(cnt + g, c);
            acc = 0.f; c = 0.f; g = bg;
        }
        acc += h[(size_t)n * 128 + t];
        c += 1.f;
    }
    atomicAdd(pooled + g * 128 + t, acc);
    if (t == 0) atomicAdd(cnt + g, c);
}

// ---- dueling heads ----
__global__ __launch_bounds__(128) void k_head(
    const float* __restrict__ pooled, const float* __restrict__ cnt,
    const float* __restrict__ Wv1, const float* __restrict__ bv1,
    const float* __restrict__ Wv2, const float* __restrict__ bv2,
    const float* __restrict__ Wa1, const float* __restrict__ ba1,
    const float* __restrict__ Wa2, const float* __restrict__ ba2,
    float* __restrict__ out)
{
    __shared__ float pr[128];
    __shared__ float hv[64];
    __shared__ float ha[64];
    __shared__ float sA[10];
    __shared__ float sVM[2];
    const int g = blockIdx.x;
    const int t = threadIdx.x;

    const float inv = 1.0f / fmaxf(cnt[g], 1.0f);
    pr[t] = pooled[g * 128 + t] * inv;
    __syncthreads();

    if (t < 64) {
        float sv = bv1[t], sa = ba1[t];
        #pragma unroll 8
        for (int k = 0; k < 128; ++k) {
            float p = pr[k];
            sv = fmaf(p, Wv1[k * 64 + t], sv);
            sa = fmaf(p, Wa1[k * 64 + t], sa);
        }
        hv[t] = fmaxf(sv, 0.0f);
        ha[t] = fmaxf(sa, 0.0f);
    }
    __syncthreads();

    if (t < 10) {
        float av = ba2[t];
        #pragma unroll
        for (int j = 0; j < 64; ++j) av = fmaf(ha[j], Wa2[j * 10 + t], av);
        sA[t] = av;
    }
    if (t == 64) {
        float v = bv2[0];
        #pragma unroll
        for (int j = 0; j < 64; ++j) v = fmaf(hv[j], Wv2[j], v);
        sVM[0] = v;
    }
    __syncthreads();

    if (t == 0) {
        float s = 0.0f;
        #pragma unroll
        for (int j = 0; j < 10; ++j) s += sA[j];
        sVM[1] = s * 0.1f;
    }
    __syncthreads();

    if (t < 10) out[g * 10 + t] = sVM[0] + sA[t] - sVM[1];
}

extern "C" void kernel_launch(void* const* d_in, const int* in_sizes, int n_in,
                              void* d_out, int out_size, void* d_ws, size_t ws_size,
                              hipStream_t stream)
{
    const float* x     = (const float*)d_in[0];
    const float* ea    = (const float*)d_in[1];
    const int*   ei    = (const int*)d_in[2];   // [2*E], row0 = src, row1 = dst
    const int*   batch = (const int*)d_in[3];

    // workspace layout
    float* ws = (float*)d_ws;
    float* xl     = ws;                              // N*128
    float* xr     = xl + (size_t)NN * 128;           // N*128
    float* hA     = xr + (size_t)NN * 128;           // N*128
    float* hB     = hA + (size_t)NN * 128;           // N*128
    float* pooled = hB + (size_t)NN * 128;           // G*128
    float* cntp   = pooled + (size_t)NG * 128;       // G
    int*   rowptr = (int*)(cntp + NG);               // NN+1
    int*   cnt    = rowptr + (NN + 1);               // NN
    int*   woff   = cnt + NN;                        // NN
    int*   eids   = woff + NN;                       // NE
    int*   esrc   = eids + NE;                       // NE

    const int EB = (NE + 255) / 256;

    // ---- CSR by destination (shared across all 3 layers) ----
    hipMemsetAsync(cnt, 0, NN * sizeof(int), stream);
    hipMemsetAsync(woff, 0, NN * sizeof(int), stream);
    k_count<<<dim3(EB), dim3(256), 0, stream>>>(ei, cnt);
    k_scan<<<dim3(1), dim3(1024), 0, stream>>>(cnt, rowptr);
    k_fill<<<dim3(EB), dim3(256), 0, stream>>>(ei, rowptr, woff, eids, esrc);

#define LAYER(DIN, DOUT, HIN, HOUT, B)                                                   \
    do {                                                                                 \
        k_node_linear<DIN, DOUT><<<dim3((NN + 15) / 16), dim3(256), 0, stream>>>(        \
            HIN, (const float*)d_in[B], (const float*)d_in[(B) + 1],                     \
            (const float*)d_in[(B) + 2], (const float*)d_in[(B) + 3], xl, xr);           \
        k_gat_fused<DOUT><<<dim3(NN), dim3(128), 0, stream>>>(                           \
            rowptr, eids, esrc, ea, xl, xr, (const float*)d_in[(B) + 4],                 \
            (const float*)d_in[(B) + 5], (const float*)d_in[(B) + 6], HOUT);             \
    } while (0)

    LAYER(128, 32, x,  hA, 4);    // layer 1: 128 -> 32
    LAYER(32,  64, hA, hB, 11);   // layer 2: 32  -> 64
    LAYER(64, 128, hB, hA, 18);   // layer 3: 64  -> 128

#undef LAYER

    hipMemsetAsync(pooled, 0, NG * 128 * sizeof(float), stream);
    hipMemsetAsync(cntp, 0, NG * sizeof(float), stream);
    k_pool<<<dim3(512), dim3(128), 0, stream>>>(hA, batch, pooled, cntp);
    k_head<<<dim3(NG), dim3(128), 0, stream>>>(
        pooled, cntp,
        (const float*)d_in[25], (const float*)d_in[26],
        (const float*)d_in[27], (const float*)d_in[28],
        (const float*)d_in[29], (const float*)d_in[30],
        (const float*)d_in[31], (const float*)d_in[32],
        (float*)d_out);
}

// Round 5
// 1098.506 us; speedup vs baseline: 19.5812x; 1.2705x over previous
//
#include <hip/hip_runtime.h>
#include <cstdint>
#include <cstddef>

static constexpr int NN = 50000;     // nodes
static constexpr int NE = 1600000;   // edges
static constexpr int NG = 64;        // graphs
static constexpr int FE = 16;        // edge feature dim
static constexpr float SLOPE = 0.2f; // leaky_relu negative slope

// ---- fused node linear: xl = h@Wl + bl, xr = h@Wr + br ----
template<int DIN, int DOUT>
__global__ __launch_bounds__(256) void k_node_linear(
    const float* __restrict__ h,
    const float* __restrict__ Wl, const float* __restrict__ bl,
    const float* __restrict__ Wr, const float* __restrict__ br,
    float* __restrict__ xl, float* __restrict__ xr)
{
    __shared__ float sW[2 * DIN * DOUT];
    __shared__ float sX[16 * DIN];
    const int n0 = blockIdx.x * 16;

    for (int i = threadIdx.x; i < DIN * DOUT; i += 256) {
        sW[i] = Wl[i];
        sW[DIN * DOUT + i] = Wr[i];
    }
    for (int i = threadIdx.x; i < 16 * DIN; i += 256) {
        int r = i / DIN, k = i % DIN;
        int n = n0 + r;
        sX[i] = (n < NN) ? h[(size_t)n * DIN + k] : 0.0f;
    }
    __syncthreads();

    for (int o = threadIdx.x; o < 16 * DOUT; o += 256) {
        int r = o / DOUT, d = o % DOUT;
        int n = n0 + r;
        if (n >= NN) continue;
        float accl = bl[d], accr = br[d];
        #pragma unroll 8
        for (int k = 0; k < DIN; ++k) {
            float xv = sX[r * DIN + k];
            accl = fmaf(xv, sW[k * DOUT + d], accl);
            accr = fmaf(xv, sW[DIN * DOUT + k * DOUT + d], accr);
        }
        xl[(size_t)n * DOUT + d] = accl;
        xr[(size_t)n * DOUT + d] = accr;
    }
}

// ---- CSR build: count / scan / fill (+ permuted src ids) ----
__global__ __launch_bounds__(256) void k_count(
    const int* __restrict__ ei, int* __restrict__ cnt)
{
    const int e = blockIdx.x * 256 + threadIdx.x;
    if (e >= NE) return;
    atomicAdd(cnt + ei[NE + e], 1);
}

__global__ __launch_bounds__(1024) void k_scan(
    const int* __restrict__ cnt, int* __restrict__ rowptr)
{
    __shared__ int part[1024];
    const int T = 1024;
    const int C = (NN + T - 1) / T;
    const int t = threadIdx.x;
    const int base = t * C;
    int s = 0;
    for (int i = 0; i < C; ++i) {
        int idx = base + i;
        if (idx < NN) s += cnt[idx];
    }
    part[t] = s;
    __syncthreads();
    for (int off = 1; off < T; off <<= 1) {
        int v = 0;
        if (t >= off) v = part[t - off];
        __syncthreads();
        if (t >= off) part[t] += v;
        __syncthreads();
    }
    int run = (t == 0) ? 0 : part[t - 1];
    for (int i = 0; i < C; ++i) {
        int idx = base + i;
        if (idx < NN) { rowptr[idx] = run; run += cnt[idx]; }
    }
    if (t == T - 1) rowptr[NN] = run;
}

__global__ __launch_bounds__(256) void k_fill(
    const int* __restrict__ ei, const int* __restrict__ rowptr,
    int* __restrict__ woff, int* __restrict__ eids, int* __restrict__ esrc)
{
    const int e = blockIdx.x * 256 + threadIdx.x;
    if (e >= NE) return;
    const int dst = ei[NE + e];
    const int pos = rowptr[dst] + atomicAdd(woff + dst, 1);
    eids[pos] = e;
    esrc[pos] = ei[e];
}

// ---- fused GATv2: score + online softmax + aggregate + bias + relu ----
// One 128-thread block (2 waves) per destination node.
// Dim-per-lane layout: lane owns dims {dl, dl+64}; We/att/xr live in REGISTERS
// (zero LDS in the inner loop). Each edge stream (wave, or half-wave for D=32)
// runs an independent register-resident online softmax; streams merge once at
// the end. xl[src] row is read exactly once per edge.
template<int D>
__global__ __launch_bounds__(128) void k_gat_fused(
    const int* __restrict__ rowptr, const int* __restrict__ eids,
    const int* __restrict__ esrc, const float* __restrict__ ea,
    const float* __restrict__ xl, const float* __restrict__ xr,
    const float* __restrict__ We, const float* __restrict__ att,
    const float* __restrict__ bo, float* __restrict__ hout)
{
    constexpr int EPW = (D >= 64) ? 1 : (64 / D);   // edge streams per wave
    constexpr int DPL = (D + 63) / 64;              // dims per lane
    constexpr int WPB = 2;                          // waves per block
    constexpr int WS  = WPB * EPW;                  // total streams

    __shared__ float sM[WS];
    __shared__ float sL2[WS];
    __shared__ float sAcc[WS][D];

    const int n = blockIdx.x;
    const int t = threadIdx.x;
    const int wave = t >> 6;
    const int lane = t & 63;
    const int sub  = (EPW == 2) ? (lane >> 5) : 0;
    const int dl   = (EPW == 2) ? (lane & 31) : lane;
    const int stream = wave * EPW + sub;

    // register-resident weights / per-node dest transform
    float rWe[FE * DPL], rAtt[DPL], rXr[DPL], acc[DPL];
    #pragma unroll
    for (int i = 0; i < DPL; ++i) {
        const int d = dl + 64 * i;
        rAtt[i] = att[d];
        rXr[i]  = xr[(size_t)n * D + d];
        acc[i]  = 0.f;
        #pragma unroll
        for (int k = 0; k < FE; ++k) rWe[k * DPL + i] = We[k * D + d];
    }

    const int p0 = rowptr[n], p1 = rowptr[n + 1];
    float m = -3.4e38f, l = 0.f;

    for (int p = p0 + stream; p < p1; p += WS) {
        const int e = eids[p];
        const int s = esrc[p];

        // edge features, broadcast to all lanes of the stream
        float eav[FE];
        if constexpr (EPW == 1) {
            // e is wave-uniform; force SGPR base -> scalar loads
            const float* eap = ea + (size_t)(unsigned)__builtin_amdgcn_readfirstlane(e) * FE;
            #pragma unroll
            for (int k = 0; k < FE; ++k) eav[k] = eap[k];
        } else {
            const float v = ea[(size_t)e * FE + (dl & 15)];
            #pragma unroll
            for (int k = 0; k < FE; ++k) eav[k] = __shfl(v, (lane & 32) + k, 64);
        }

        // message + score partial (pure register FMAs)
        float rXl[DPL];
        float sv = 0.f;
        #pragma unroll
        for (int i = 0; i < DPL; ++i) {
            rXl[i] = xl[(size_t)s * D + dl + 64 * i];
            float mm = rXl[i] + rXr[i];
            #pragma unroll
            for (int k = 0; k < FE; ++k) mm = fmaf(eav[k], rWe[k * DPL + i], mm);
            mm = mm > 0.f ? mm : SLOPE * mm;
            sv = fmaf(mm, rAtt[i], sv);
        }
        // reduce across the stream's lanes
        sv += __shfl_xor(sv, 1);
        sv += __shfl_xor(sv, 2);
        sv += __shfl_xor(sv, 4);
        sv += __shfl_xor(sv, 8);
        sv += __shfl_xor(sv, 16);
        if constexpr (EPW == 1) sv += __shfl_xor(sv, 32);

        // online softmax update (1 exp in the common non-max case)
        float wexp;
        if (sv > m) {
            const float r = __expf(m - sv);
            #pragma unroll
            for (int i = 0; i < DPL; ++i) acc[i] *= r;
            l *= r; m = sv; wexp = 1.f;
        } else {
            wexp = __expf(sv - m);
        }
        #pragma unroll
        for (int i = 0; i < DPL; ++i) acc[i] = fmaf(wexp, rXl[i], acc[i]);
        l += wexp;
    }

    // ---- merge streams ----
    if (dl == 0) sM[stream] = m;
    __syncthreads();
    float mstar = sM[0];
    #pragma unroll
    for (int s2 = 1; s2 < WS; ++s2) mstar = fmaxf(mstar, sM[s2]);
    const float scale = __expf(m - mstar);   // 0 for empty streams
    #pragma unroll
    for (int i = 0; i < DPL; ++i) sAcc[stream][dl + 64 * i] = acc[i] * scale;
    if (dl == 0) sL2[stream] = l * scale;
    __syncthreads();

    if (t < D) {
        float a = 0.f, lt = 1e-16f;
        #pragma unroll
        for (int s2 = 0; s2 < WS; ++s2) { a += sAcc[s2][t]; lt += sL2[s2]; }
        hout[(size_t)n * D + t] = fmaxf(a / lt + bo[t], 0.f);
    }
}

// ---- global mean pool: run-length reduction over sorted batch ----
__global__ __launch_bounds__(128) void k_pool(
    const float* __restrict__ h, const int* __restrict__ batch,
    float* __restrict__ pooled, float* __restrict__ cnt)
{
    constexpr int BLOCKS = 512;
    constexpr int CH = (NN + BLOCKS - 1) / BLOCKS;
    const int t = threadIdx.x;
    const int n0 = blockIdx.x * CH;
    const int n1 = min(NN, n0 + CH);
    if (n0 >= n1) return;

    int g = batch[n0];
    float acc = 0.f, c = 0.f;
    for (int n = n0; n < n1; ++n) {
        const int bg = batch[n];
        if (bg != g) {
            atomicAdd(pooled + g * 128 + t, acc);
            if (t == 0) atomicAdd(cnt + g, c);
            acc = 0.f; c = 0.f; g = bg;
        }
        acc += h[(size_t)n * 128 + t];
        c += 1.f;
    }
    atomicAdd(pooled + g * 128 + t, acc);
    if (t == 0) atomicAdd(cnt + g, c);
}

// ---- dueling heads ----
__global__ __launch_bounds__(128) void k_head(
    const float* __restrict__ pooled, const float* __restrict__ cnt,
    const float* __restrict__ Wv1, const float* __restrict__ bv1,
    const float* __restrict__ Wv2, const float* __restrict__ bv2,
    const float* __restrict__ Wa1, const float* __restrict__ ba1,
    const float* __restrict__ Wa2, const float* __restrict__ ba2,
    float* __restrict__ out)
{
    __shared__ float pr[128];
    __shared__ float hv[64];
    __shared__ float ha[64];
    __shared__ float sA[10];
    __shared__ float sVM[2];
    const int g = blockIdx.x;
    const int t = threadIdx.x;

    const float inv = 1.0f / fmaxf(cnt[g], 1.0f);
    pr[t] = pooled[g * 128 + t] * inv;
    __syncthreads();

    if (t < 64) {
        float sv = bv1[t], sa = ba1[t];
        #pragma unroll 8
        for (int k = 0; k < 128; ++k) {
            float p = pr[k];
            sv = fmaf(p, Wv1[k * 64 + t], sv);
            sa = fmaf(p, Wa1[k * 64 + t], sa);
        }
        hv[t] = fmaxf(sv, 0.0f);
        ha[t] = fmaxf(sa, 0.0f);
    }
    __syncthreads();

    if (t < 10) {
        float av = ba2[t];
        #pragma unroll
        for (int j = 0; j < 64; ++j) av = fmaf(ha[j], Wa2[j * 10 + t], av);
        sA[t] = av;
    }
    if (t == 64) {
        float v = bv2[0];
        #pragma unroll
        for (int j = 0; j < 64; ++j) v = fmaf(hv[j], Wv2[j], v);
        sVM[0] = v;
    }
    __syncthreads();

    if (t == 0) {
        float s = 0.0f;
        #pragma unroll
        for (int j = 0; j < 10; ++j) s += sA[j];
        sVM[1] = s * 0.1f;
    }
    __syncthreads();

    if (t < 10) out[g * 10 + t] = sVM[0] + sA[t] - sVM[1];
}

extern "C" void kernel_launch(void* const* d_in, const int* in_sizes, int n_in,
                              void* d_out, int out_size, void* d_ws, size_t ws_size,
                              hipStream_t stream)
{
    const float* x     = (const float*)d_in[0];
    const float* ea    = (const float*)d_in[1];
    const int*   ei    = (const int*)d_in[2];   // [2*E], row0 = src, row1 = dst
    const int*   batch = (const int*)d_in[3];

    // workspace layout
    float* ws = (float*)d_ws;
    float* xl     = ws;                              // N*128
    float* xr     = xl + (size_t)NN * 128;           // N*128
    float* hA     = xr + (size_t)NN * 128;           // N*128
    float* hB     = hA + (size_t)NN * 128;           // N*128
    float* pooled = hB + (size_t)NN * 128;           // G*128
    float* cntp   = pooled + (size_t)NG * 128;       // G
    int*   rowptr = (int*)(cntp + NG);               // NN+1
    int*   cnt    = rowptr + (NN + 1);               // NN
    int*   woff   = cnt + NN;                        // NN
    int*   eids   = woff + NN;                       // NE
    int*   esrc   = eids + NE;                       // NE

    const int EB = (NE + 255) / 256;

    // ---- CSR by destination (shared across all 3 layers) ----
    hipMemsetAsync(cnt, 0, NN * sizeof(int), stream);
    hipMemsetAsync(woff, 0, NN * sizeof(int), stream);
    k_count<<<dim3(EB), dim3(256), 0, stream>>>(ei, cnt);
    k_scan<<<dim3(1), dim3(1024), 0, stream>>>(cnt, rowptr);
    k_fill<<<dim3(EB), dim3(256), 0, stream>>>(ei, rowptr, woff, eids, esrc);

#define LAYER(DIN, DOUT, HIN, HOUT, B)                                                   \
    do {                                                                                 \
        k_node_linear<DIN, DOUT><<<dim3((NN + 15) / 16), dim3(256), 0, stream>>>(        \
            HIN, (const float*)d_in[B], (const float*)d_in[(B) + 1],                     \
            (const float*)d_in[(B) + 2], (const float*)d_in[(B) + 3], xl, xr);           \
        k_gat_fused<DOUT><<<dim3(NN), dim3(128), 0, stream>>>(                           \
            rowptr, eids, esrc, ea, xl, xr, (const float*)d_in[(B) + 4],                 \
            (const float*)d_in[(B) + 5], (const float*)d_in[(B) + 6], HOUT);             \
    } while (0)

    LAYER(128, 32, x,  hA, 4);    // layer 1: 128 -> 32
    LAYER(32,  64, hA, hB, 11);   // layer 2: 32  -> 64
    LAYER(64, 128, hB, hA, 18);   // layer 3: 64  -> 128

#undef LAYER

    hipMemsetAsync(pooled, 0, NG * 128 * sizeof(float), stream);
    hipMemsetAsync(cntp, 0, NG * sizeof(float), stream);
    k_pool<<<dim3(512), dim3(128), 0, stream>>>(hA, batch, pooled, cntp);
    k_head<<<dim3(NG), dim3(128), 0, stream>>>(
        pooled, cntp,
        (const float*)d_in[25], (const float*)d_in[26],
        (const float*)d_in[27], (const float*)d_in[28],
        (const float*)d_in[29], (const float*)d_in[30],
        (const float*)d_in[31], (const float*)d_in[32],
        (float*)d_out);
}

// Round 6
// 1059.978 us; speedup vs baseline: 20.2929x; 1.0363x over previous
//
#include <hip/hip_runtime.h>
#include <cstdint>
#include <cstddef>

static constexpr int NN = 50000;     // nodes
static constexpr int NE = 1600000;   // edges
static constexpr int NG = 64;        // graphs
static constexpr int FE = 16;        // edge feature dim
static constexpr float SLOPE = 0.2f; // leaky_relu negative slope

// ---- fused node linear: xl = h@Wl + bl, xr = h@Wr + br ----
template<int DIN, int DOUT>
__global__ __launch_bounds__(256) void k_node_linear(
    const float* __restrict__ h,
    const float* __restrict__ Wl, const float* __restrict__ bl,
    const float* __restrict__ Wr, const float* __restrict__ br,
    float* __restrict__ xl, float* __restrict__ xr)
{
    __shared__ float sW[2 * DIN * DOUT];
    __shared__ float sX[16 * DIN];
    const int n0 = blockIdx.x * 16;

    for (int i = threadIdx.x; i < DIN * DOUT; i += 256) {
        sW[i] = Wl[i];
        sW[DIN * DOUT + i] = Wr[i];
    }
    for (int i = threadIdx.x; i < 16 * DIN; i += 256) {
        int r = i / DIN, k = i % DIN;
        int n = n0 + r;
        sX[i] = (n < NN) ? h[(size_t)n * DIN + k] : 0.0f;
    }
    __syncthreads();

    for (int o = threadIdx.x; o < 16 * DOUT; o += 256) {
        int r = o / DOUT, d = o % DOUT;
        int n = n0 + r;
        if (n >= NN) continue;
        float accl = bl[d], accr = br[d];
        #pragma unroll 8
        for (int k = 0; k < DIN; ++k) {
            float xv = sX[r * DIN + k];
            accl = fmaf(xv, sW[k * DOUT + d], accl);
            accr = fmaf(xv, sW[DIN * DOUT + k * DOUT + d], accr);
        }
        xl[(size_t)n * DOUT + d] = accl;
        xr[(size_t)n * DOUT + d] = accr;
    }
}

// ---- CSR build: count / scan / fill (+ permuted src ids) ----
__global__ __launch_bounds__(256) void k_count(
    const int* __restrict__ ei, int* __restrict__ cnt)
{
    const int e = blockIdx.x * 256 + threadIdx.x;
    if (e >= NE) return;
    atomicAdd(cnt + ei[NE + e], 1);
}

__global__ __launch_bounds__(1024) void k_scan(
    const int* __restrict__ cnt, int* __restrict__ rowptr)
{
    __shared__ int part[1024];
    const int T = 1024;
    const int C = (NN + T - 1) / T;
    const int t = threadIdx.x;
    const int base = t * C;
    int s = 0;
    for (int i = 0; i < C; ++i) {
        int idx = base + i;
        if (idx < NN) s += cnt[idx];
    }
    part[t] = s;
    __syncthreads();
    for (int off = 1; off < T; off <<= 1) {
        int v = 0;
        if (t >= off) v = part[t - off];
        __syncthreads();
        if (t >= off) part[t] += v;
        __syncthreads();
    }
    int run = (t == 0) ? 0 : part[t - 1];
    for (int i = 0; i < C; ++i) {
        int idx = base + i;
        if (idx < NN) { rowptr[idx] = run; run += cnt[idx]; }
    }
    if (t == T - 1) rowptr[NN] = run;
}

__global__ __launch_bounds__(256) void k_fill(
    const int* __restrict__ ei, const int* __restrict__ rowptr,
    int* __restrict__ woff, int* __restrict__ eids, int* __restrict__ esrc)
{
    const int e = blockIdx.x * 256 + threadIdx.x;
    if (e >= NE) return;
    const int dst = ei[NE + e];
    const int pos = rowptr[dst] + atomicAdd(woff + dst, 1);
    eids[pos] = e;
    esrc[pos] = ei[e];
}

// ---- one-time CSR-order gather of edge features (coalesced writes) ----
__global__ __launch_bounds__(256) void k_gather_ea(
    const int* __restrict__ eids, const float* __restrict__ ea,
    float* __restrict__ eap)
{
    const long long i = (long long)blockIdx.x * 256 + threadIdx.x;  // p*4 + q
    if (i >= (long long)NE * 4) return;
    const int p = (int)(i >> 2), q = (int)(i & 3);
    const int e = eids[p];
    *(float4*)(eap + (size_t)p * FE + q * 4) =
        *(const float4*)(ea + (size_t)e * FE + q * 4);
}

// ---- fused GATv2: score + online softmax + aggregate + bias + relu ----
// One 128-thread block (2 waves) per destination node.
// Sub-wave edge streams of SW lanes; each lane owns 2 dims {dl, dl+SW}.
// We/att/xr in registers; zero LDS in the main loop; xl row read once/edge.
// PERM: edge features pre-permuted to CSR order (sequential reads, no eids).
template<int D, bool PERM>
__global__ __launch_bounds__(128) void k_gat_fused(
    const int* __restrict__ rowptr, const int* __restrict__ eidx,
    const int* __restrict__ esrc, const float* __restrict__ eaf,
    const float* __restrict__ xl, const float* __restrict__ xr,
    const float* __restrict__ We, const float* __restrict__ att,
    const float* __restrict__ bo, float* __restrict__ hout)
{
    constexpr int SW  = (D >= 128) ? 64 : (D >= 64 ? 32 : 16);  // stream width
    constexpr int EPW = 64 / SW;    // streams per wave
    constexpr int DPL = D / SW;     // dims per lane (= 2)
    constexpr int WPB = 2;          // waves per block
    constexpr int WS  = WPB * EPW;  // total streams

    __shared__ float sM[WS];
    __shared__ float sL2[WS];
    __shared__ float sAcc[WS][D];

    const int n = blockIdx.x;
    const int t = threadIdx.x;
    const int wave = t >> 6;
    const int lane = t & 63;
    const int sub  = lane / SW;
    const int dl   = lane % SW;
    const int lbase = lane - dl;
    const int stream = wave * EPW + sub;

    // register-resident weights / per-node dest transform
    float rWe[FE * DPL], rAtt[DPL], rXr[DPL], acc[DPL];
    #pragma unroll
    for (int i = 0; i < DPL; ++i) {
        const int d = dl + SW * i;
        rAtt[i] = att[d];
        rXr[i]  = xr[(size_t)n * D + d];
        acc[i]  = 0.f;
        #pragma unroll
        for (int k = 0; k < FE; ++k) rWe[k * DPL + i] = We[k * D + d];
    }

    const int p0 = rowptr[n], p1 = rowptr[n + 1];
    float m = -3.4e38f, l = 0.f;

    for (int p = p0 + stream; p < p1; p += WS) {
        const int s = esrc[p];
        int erow;
        if constexpr (PERM) erow = p; else erow = eidx[p];

        // edge features, broadcast to all lanes of the stream
        float eav[FE];
        if constexpr (SW == 64) {
            // row index is wave-uniform; force SGPR base -> scalar loads
            const float* ep = eaf + (size_t)(unsigned)__builtin_amdgcn_readfirstlane(erow) * FE;
            #pragma unroll
            for (int k = 0; k < FE; ++k) eav[k] = ep[k];
        } else {
            const float v = eaf[(size_t)erow * FE + (dl & 15)];
            #pragma unroll
            for (int k = 0; k < FE; ++k) eav[k] = __shfl(v, lbase + k, 64);
        }

        // message + score partial (pure register FMAs)
        float rXl[DPL];
        float sv = 0.f;
        #pragma unroll
        for (int i = 0; i < DPL; ++i) {
            rXl[i] = xl[(size_t)s * D + dl + SW * i];
            float mm = rXl[i] + rXr[i];
            #pragma unroll
            for (int k = 0; k < FE; ++k) mm = fmaf(eav[k], rWe[k * DPL + i], mm);
            mm = mm > 0.f ? mm : SLOPE * mm;
            sv = fmaf(mm, rAtt[i], sv);
        }
        // reduce across the stream's SW lanes
        #pragma unroll
        for (int off = 1; off < SW; off <<= 1) sv += __shfl_xor(sv, off);

        // online softmax update (1 exp in the common non-max case)
        float wexp;
        if (sv > m) {
            const float r = __expf(m - sv);
            #pragma unroll
            for (int i = 0; i < DPL; ++i) acc[i] *= r;
            l *= r; m = sv; wexp = 1.f;
        } else {
            wexp = __expf(sv - m);
        }
        #pragma unroll
        for (int i = 0; i < DPL; ++i) acc[i] = fmaf(wexp, rXl[i], acc[i]);
        l += wexp;
    }

    // ---- merge streams ----
    if (dl == 0) sM[stream] = m;
    __syncthreads();
    float mstar = sM[0];
    #pragma unroll
    for (int s2 = 1; s2 < WS; ++s2) mstar = fmaxf(mstar, sM[s2]);
    const float scale = __expf(m - mstar);   // 0 for empty streams
    #pragma unroll
    for (int i = 0; i < DPL; ++i) sAcc[stream][dl + SW * i] = acc[i] * scale;
    if (dl == 0) sL2[stream] = l * scale;
    __syncthreads();

    if (t < D) {
        float a = 0.f, lt = 1e-16f;
        #pragma unroll
        for (int s2 = 0; s2 < WS; ++s2) { a += sAcc[s2][t]; lt += sL2[s2]; }
        hout[(size_t)n * D + t] = fmaxf(a / lt + bo[t], 0.f);
    }
}

// ---- global mean pool: run-length reduction over sorted batch ----
__global__ __launch_bounds__(128) void k_pool(
    const float* __restrict__ h, const int* __restrict__ batch,
    float* __restrict__ pooled, float* __restrict__ cnt)
{
    constexpr int BLOCKS = 512;
    constexpr int CH = (NN + BLOCKS - 1) / BLOCKS;
    const int t = threadIdx.x;
    const int n0 = blockIdx.x * CH;
    const int n1 = min(NN, n0 + CH);
    if (n0 >= n1) return;

    int g = batch[n0];
    float acc = 0.f, c = 0.f;
    for (int n = n0; n < n1; ++n) {
        const int bg = batch[n];
        if (bg != g) {
            atomicAdd(pooled + g * 128 + t, acc);
            if (t == 0) atomicAdd(cnt + g, c);
            acc = 0.f; c = 0.f; g = bg;
        }
        acc += h[(size_t)n * 128 + t];
        c += 1.f;
    }
    atomicAdd(pooled + g * 128 + t, acc);
    if (t == 0) atomicAdd(cnt + g, c);
}

// ---- dueling heads ----
__global__ __launch_bounds__(128) void k_head(
    const float* __restrict__ pooled, const float* __restrict__ cnt,
    const float* __restrict__ Wv1, const float* __restrict__ bv1,
    const float* __restrict__ Wv2, const float* __restrict__ bv2,
    const float* __restrict__ Wa1, const float* __restrict__ ba1,
    const float* __restrict__ Wa2, const float* __restrict__ ba2,
    float* __restrict__ out)
{
    __shared__ float pr[128];
    __shared__ float hv[64];
    __shared__ float ha[64];
    __shared__ float sA[10];
    __shared__ float sVM[2];
    const int g = blockIdx.x;
    const int t = threadIdx.x;

    const float inv = 1.0f / fmaxf(cnt[g], 1.0f);
    pr[t] = pooled[g * 128 + t] * inv;
    __syncthreads();

    if (t < 64) {
        float sv = bv1[t], sa = ba1[t];
        #pragma unroll 8
        for (int k = 0; k < 128; ++k) {
            float p = pr[k];
            sv = fmaf(p, Wv1[k * 64 + t], sv);
            sa = fmaf(p, Wa1[k * 64 + t], sa);
        }
        hv[t] = fmaxf(sv, 0.0f);
        ha[t] = fmaxf(sa, 0.0f);
    }
    __syncthreads();

    if (t < 10) {
        float av = ba2[t];
        #pragma unroll
        for (int j = 0; j < 64; ++j) av = fmaf(ha[j], Wa2[j * 10 + t], av);
        sA[t] = av;
    }
    if (t == 64) {
        float v = bv2[0];
        #pragma unroll
        for (int j = 0; j < 64; ++j) v = fmaf(hv[j], Wv2[j], v);
        sVM[0] = v;
    }
    __syncthreads();

    if (t == 0) {
        float s = 0.0f;
        #pragma unroll
        for (int j = 0; j < 10; ++j) s += sA[j];
        sVM[1] = s * 0.1f;
    }
    __syncthreads();

    if (t < 10) out[g * 10 + t] = sVM[0] + sA[t] - sVM[1];
}

extern "C" void kernel_launch(void* const* d_in, const int* in_sizes, int n_in,
                              void* d_out, int out_size, void* d_ws, size_t ws_size,
                              hipStream_t stream)
{
    const float* x     = (const float*)d_in[0];
    const float* ea    = (const float*)d_in[1];
    const int*   ei    = (const int*)d_in[2];   // [2*E], row0 = src, row1 = dst
    const int*   batch = (const int*)d_in[3];

    // workspace layout
    float* ws = (float*)d_ws;
    float* xl     = ws;                              // N*128
    float* xr     = xl + (size_t)NN * 128;           // N*128
    float* hA     = xr + (size_t)NN * 128;           // N*128
    float* hB     = hA + (size_t)NN * 128;           // N*128
    float* pooled = hB + (size_t)NN * 128;           // G*128
    float* cntp   = pooled + (size_t)NG * 128;       // G
    int*   rowptr = (int*)(cntp + NG);               // NN+1
    int*   cnt    = rowptr + (NN + 1);               // NN
    int*   woff   = cnt + NN;                        // NN
    int*   eids   = woff + NN;                       // NE
    int*   esrc   = eids + NE;                       // NE
    float* eaperm = (float*)(esrc + NE);             // NE*FE (optional)

    const size_t need = ((char*)(eaperm + (size_t)NE * FE)) - (char*)d_ws;
    const bool use_perm = (ws_size >= need);

    const int EB = (NE + 255) / 256;

    // ---- CSR by destination (shared across all 3 layers) ----
    hipMemsetAsync(cnt, 0, NN * sizeof(int), stream);
    hipMemsetAsync(woff, 0, NN * sizeof(int), stream);
    k_count<<<dim3(EB), dim3(256), 0, stream>>>(ei, cnt);
    k_scan<<<dim3(1), dim3(1024), 0, stream>>>(cnt, rowptr);
    k_fill<<<dim3(EB), dim3(256), 0, stream>>>(ei, rowptr, woff, eids, esrc);
    if (use_perm) {
        const long long tot = (long long)NE * 4;
        k_gather_ea<<<dim3((unsigned)((tot + 255) / 256)), dim3(256), 0, stream>>>(
            eids, ea, eaperm);
    }

#define LAYER(DIN, DOUT, HIN, HOUT, B)                                                   \
    do {                                                                                 \
        k_node_linear<DIN, DOUT><<<dim3((NN + 15) / 16), dim3(256), 0, stream>>>(        \
            HIN, (const float*)d_in[B], (const float*)d_in[(B) + 1],                     \
            (const float*)d_in[(B) + 2], (const float*)d_in[(B) + 3], xl, xr);           \
        if (use_perm)                                                                    \
            k_gat_fused<DOUT, true><<<dim3(NN), dim3(128), 0, stream>>>(                 \
                rowptr, eids, esrc, eaperm, xl, xr, (const float*)d_in[(B) + 4],         \
                (const float*)d_in[(B) + 5], (const float*)d_in[(B) + 6], HOUT);         \
        else                                                                             \
            k_gat_fused<DOUT, false><<<dim3(NN), dim3(128), 0, stream>>>(                \
                rowptr, eids, esrc, ea, xl, xr, (const float*)d_in[(B) + 4],             \
                (const float*)d_in[(B) + 5], (const float*)d_in[(B) + 6], HOUT);         \
    } while (0)

    LAYER(128, 32, x,  hA, 4);    // layer 1: 128 -> 32
    LAYER(32,  64, hA, hB, 11);   // layer 2: 32  -> 64
    LAYER(64, 128, hB, hA, 18);   // layer 3: 64  -> 128

#undef LAYER

    hipMemsetAsync(pooled, 0, NG * 128 * sizeof(float), stream);
    hipMemsetAsync(cntp, 0, NG * sizeof(float), stream);
    k_pool<<<dim3(512), dim3(128), 0, stream>>>(hA, batch, pooled, cntp);
    k_head<<<dim3(NG), dim3(128), 0, stream>>>(
        pooled, cntp,
        (const float*)d_in[25], (const float*)d_in[26],
        (const float*)d_in[27], (const float*)d_in[28],
        (const float*)d_in[29], (const float*)d_in[30],
        (const float*)d_in[31], (const float*)d_in[32],
        (float*)d_out);
}

// Round 7
// 1013.947 us; speedup vs baseline: 21.2142x; 1.0454x over previous
//
#include <hip/hip_runtime.h>
#include <cstdint>
#include <cstddef>

static constexpr int NN = 50000;     // nodes
static constexpr int NE = 1600000;   // edges
static constexpr int NG = 64;        // graphs
static constexpr int FE = 16;        // edge feature dim
static constexpr float SLOPE = 0.2f; // leaky_relu negative slope

// ---- fused node linear: xl = h@Wl + bl, xr = h@Wr + br ----
template<int DIN, int DOUT>
__global__ __launch_bounds__(256) void k_node_linear(
    const float* __restrict__ h,
    const float* __restrict__ Wl, const float* __restrict__ bl,
    const float* __restrict__ Wr, const float* __restrict__ br,
    float* __restrict__ xl, float* __restrict__ xr)
{
    __shared__ float sW[2 * DIN * DOUT];
    __shared__ float sX[16 * DIN];
    const int n0 = blockIdx.x * 16;

    for (int i = threadIdx.x; i < DIN * DOUT; i += 256) {
        sW[i] = Wl[i];
        sW[DIN * DOUT + i] = Wr[i];
    }
    for (int i = threadIdx.x; i < 16 * DIN; i += 256) {
        int r = i / DIN, k = i % DIN;
        int n = n0 + r;
        sX[i] = (n < NN) ? h[(size_t)n * DIN + k] : 0.0f;
    }
    __syncthreads();

    for (int o = threadIdx.x; o < 16 * DOUT; o += 256) {
        int r = o / DOUT, d = o % DOUT;
        int n = n0 + r;
        if (n >= NN) continue;
        float accl = bl[d], accr = br[d];
        #pragma unroll 8
        for (int k = 0; k < DIN; ++k) {
            float xv = sX[r * DIN + k];
            accl = fmaf(xv, sW[k * DOUT + d], accl);
            accr = fmaf(xv, sW[DIN * DOUT + k * DOUT + d], accr);
        }
        xl[(size_t)n * DOUT + d] = accl;
        xr[(size_t)n * DOUT + d] = accr;
    }
}

// ---- CSR build: count / scan / fill (+ permuted src ids) ----
__global__ __launch_bounds__(256) void k_count(
    const int* __restrict__ ei, int* __restrict__ cnt)
{
    const int e = blockIdx.x * 256 + threadIdx.x;
    if (e >= NE) return;
    atomicAdd(cnt + ei[NE + e], 1);
}

__global__ __launch_bounds__(1024) void k_scan(
    const int* __restrict__ cnt, int* __restrict__ rowptr)
{
    __shared__ int part[1024];
    const int T = 1024;
    const int C = (NN + T - 1) / T;
    const int t = threadIdx.x;
    const int base = t * C;
    int s = 0;
    for (int i = 0; i < C; ++i) {
        int idx = base + i;
        if (idx < NN) s += cnt[idx];
    }
    part[t] = s;
    __syncthreads();
    for (int off = 1; off < T; off <<= 1) {
        int v = 0;
        if (t >= off) v = part[t - off];
        __syncthreads();
        if (t >= off) part[t] += v;
        __syncthreads();
    }
    int run = (t == 0) ? 0 : part[t - 1];
    for (int i = 0; i < C; ++i) {
        int idx = base + i;
        if (idx < NN) { rowptr[idx] = run; run += cnt[idx]; }
    }
    if (t == T - 1) rowptr[NN] = run;
}

__global__ __launch_bounds__(256) void k_fill(
    const int* __restrict__ ei, const int* __restrict__ rowptr,
    int* __restrict__ woff, int* __restrict__ eids, int* __restrict__ esrc)
{
    const int e = blockIdx.x * 256 + threadIdx.x;
    if (e >= NE) return;
    const int dst = ei[NE + e];
    const int pos = rowptr[dst] + atomicAdd(woff + dst, 1);
    eids[pos] = e;
    esrc[pos] = ei[e];
}

// ---- one-time CSR-order gather of edge features (coalesced writes) ----
__global__ __launch_bounds__(256) void k_gather_ea(
    const int* __restrict__ eids, const float* __restrict__ ea,
    float* __restrict__ eap)
{
    const long long i = (long long)blockIdx.x * 256 + threadIdx.x;  // p*4 + q
    if (i >= (long long)NE * 4) return;
    const int p = (int)(i >> 2), q = (int)(i & 3);
    const int e = eids[p];
    *(float4*)(eap + (size_t)p * FE + q * 4) =
        *(const float4*)(ea + (size_t)e * FE + q * 4);
}

// ---- fused GATv2: score + online softmax + aggregate + bias + relu ----
// One 128-thread block (2 waves) per destination node.
// Sub-wave edge streams of SW lanes; lane owns dims {dl, dl+SW}.
// __launch_bounds__(128,4): VGPR cap 128 so rWe[32]/rAtt/rXr stay REGISTER-
// resident (at the default cap the compiler re-loaded We per edge: R6 showed
// VGPR_Count=32 < the 45+ live floats). 2-edge unroll for MLP; defer-max
// (THR=8) keeps the common path branch-free with one exp per edge.
template<int D, bool PERM>
__global__ __launch_bounds__(128, 4) void k_gat_fused(
    const int* __restrict__ rowptr, const int* __restrict__ eidx,
    const int* __restrict__ esrc, const float* __restrict__ eaf,
    const float* __restrict__ xl, const float* __restrict__ xr,
    const float* __restrict__ We, const float* __restrict__ att,
    const float* __restrict__ bo, float* __restrict__ hout)
{
    constexpr int SW  = (D >= 128) ? 64 : (D >= 64 ? 32 : 16);  // stream width
    constexpr int EPW = 64 / SW;    // streams per wave
    constexpr int DPL = D / SW;     // dims per lane (= 2)
    constexpr int WPB = 2;          // waves per block
    constexpr int WS  = WPB * EPW;  // total streams

    __shared__ float sM[WS];
    __shared__ float sL2[WS];
    __shared__ float sAcc[WS][D];

    const int n = blockIdx.x;
    const int t = threadIdx.x;
    const int wave = t >> 6;
    const int lane = t & 63;
    const int sub  = lane / SW;
    const int dl   = lane % SW;
    const int lbase = lane - dl;
    const int stream = wave * EPW + sub;

    // register-resident weights / per-node dest transform
    float rWe[FE * DPL], rAtt[DPL], rXr[DPL], acc[DPL];
    #pragma unroll
    for (int i = 0; i < DPL; ++i) {
        const int d = dl + SW * i;
        rAtt[i] = att[d];
        rXr[i]  = xr[(size_t)n * D + d];
        acc[i]  = 0.f;
        #pragma unroll
        for (int k = 0; k < FE; ++k) rWe[k * DPL + i] = We[k * D + d];
    }

    const int p0 = rowptr[n], p1 = rowptr[n + 1];
    float m = -3.4e38f, l = 0.f;

    auto load_edge = [&](int p, float (&eav)[FE], float (&rXl)[DPL]) {
        const int s = esrc[p];
        int erow; if constexpr (PERM) erow = p; else erow = eidx[p];
        #pragma unroll
        for (int i = 0; i < DPL; ++i)
            rXl[i] = xl[(size_t)s * D + dl + SW * i];
        if constexpr (SW == 64) {
            // row index wave-uniform; force SGPR base -> scalar loads
            const float* ep = eaf + (size_t)(unsigned)__builtin_amdgcn_readfirstlane(erow) * FE;
            #pragma unroll
            for (int k = 0; k < FE; ++k) eav[k] = ep[k];
        } else {
            const float v = eaf[(size_t)erow * FE + (dl & 15)];
            #pragma unroll
            for (int k = 0; k < FE; ++k) eav[k] = __shfl(v, lbase + k, 64);
        }
    };
    auto score_edge = [&](const float (&eav)[FE], const float (&rXl)[DPL]) -> float {
        float sv = 0.f;
        #pragma unroll
        for (int i = 0; i < DPL; ++i) {
            float mm = rXl[i] + rXr[i];
            #pragma unroll
            for (int k = 0; k < FE; ++k) mm = fmaf(eav[k], rWe[k * DPL + i], mm);
            mm = mm > 0.f ? mm : SLOPE * mm;
            sv = fmaf(mm, rAtt[i], sv);
        }
        #pragma unroll
        for (int off = 1; off < SW; off <<= 1) sv += __shfl_xor(sv, off);
        return sv;
    };
    auto sm_update = [&](float sv, const float (&rXl)[DPL]) {
        const float dd = sv - m;
        float wexp;
        if (__builtin_expect(dd > 8.f, 0)) {
            // rare: max grew by >8 -> rescale (exp(-dd)=0 handles first edge)
            const float r = __expf(-dd);
            #pragma unroll
            for (int i = 0; i < DPL; ++i) acc[i] *= r;
            l *= r; m = sv; wexp = 1.f;
        } else {
            wexp = __expf(dd);   // bounded by e^8
        }
        #pragma unroll
        for (int i = 0; i < DPL; ++i) acc[i] = fmaf(wexp, rXl[i], acc[i]);
        l += wexp;
    };

    int p = p0 + stream;
    for (; p + WS < p1; p += 2 * WS) {
        float eavA[FE], rXlA[DPL], eavB[FE], rXlB[DPL];
        load_edge(p, eavA, rXlA);
        load_edge(p + WS, eavB, rXlB);
        const float svA = score_edge(eavA, rXlA);
        const float svB = score_edge(eavB, rXlB);
        sm_update(svA, rXlA);
        sm_update(svB, rXlB);
    }
    if (p < p1) {
        float eav[FE], rXl[DPL];
        load_edge(p, eav, rXl);
        sm_update(score_edge(eav, rXl), rXl);
    }

    // ---- merge streams ----
    if (dl == 0) sM[stream] = m;
    __syncthreads();
    float mstar = sM[0];
    #pragma unroll
    for (int s2 = 1; s2 < WS; ++s2) mstar = fmaxf(mstar, sM[s2]);
    const float scale = __expf(m - mstar);   // 0 for empty streams
    #pragma unroll
    for (int i = 0; i < DPL; ++i) sAcc[stream][dl + SW * i] = acc[i] * scale;
    if (dl == 0) sL2[stream] = l * scale;
    __syncthreads();

    if (t < D) {
        float a = 0.f, lt = 1e-16f;
        #pragma unroll
        for (int s2 = 0; s2 < WS; ++s2) { a += sAcc[s2][t]; lt += sL2[s2]; }
        hout[(size_t)n * D + t] = fmaxf(a / lt + bo[t], 0.f);
    }
}

// ---- global mean pool: run-length reduction over sorted batch ----
__global__ __launch_bounds__(128) void k_pool(
    const float* __restrict__ h, const int* __restrict__ batch,
    float* __restrict__ pooled, float* __restrict__ cnt)
{
    constexpr int BLOCKS = 512;
    constexpr int CH = (NN + BLOCKS - 1) / BLOCKS;
    const int t = threadIdx.x;
    const int n0 = blockIdx.x * CH;
    const int n1 = min(NN, n0 + CH);
    if (n0 >= n1) return;

    int g = batch[n0];
    float acc = 0.f, c = 0.f;
    for (int n = n0; n < n1; ++n) {
        const int bg = batch[n];
        if (bg != g) {
            atomicAdd(pooled + g * 128 + t, acc);
            if (t == 0) atomicAdd(cnt + g, c);
            acc = 0.f; c = 0.f; g = bg;
        }
        acc += h[(size_t)n * 128 + t];
        c += 1.f;
    }
    atomicAdd(pooled + g * 128 + t, acc);
    if (t == 0) atomicAdd(cnt + g, c);
}

// ---- dueling heads ----
__global__ __launch_bounds__(128) void k_head(
    const float* __restrict__ pooled, const float* __restrict__ cnt,
    const float* __restrict__ Wv1, const float* __restrict__ bv1,
    const float* __restrict__ Wv2, const float* __restrict__ bv2,
    const float* __restrict__ Wa1, const float* __restrict__ ba1,
    const float* __restrict__ Wa2, const float* __restrict__ ba2,
    float* __restrict__ out)
{
    __shared__ float pr[128];
    __shared__ float hv[64];
    __shared__ float ha[64];
    __shared__ float sA[10];
    __shared__ float sVM[2];
    const int g = blockIdx.x;
    const int t = threadIdx.x;

    const float inv = 1.0f / fmaxf(cnt[g], 1.0f);
    pr[t] = pooled[g * 128 + t] * inv;
    __syncthreads();

    if (t < 64) {
        float sv = bv1[t], sa = ba1[t];
        #pragma unroll 8
        for (int k = 0; k < 128; ++k) {
            float p = pr[k];
            sv = fmaf(p, Wv1[k * 64 + t], sv);
            sa = fmaf(p, Wa1[k * 64 + t], sa);
        }
        hv[t] = fmaxf(sv, 0.0f);
        ha[t] = fmaxf(sa, 0.0f);
    }
    __syncthreads();

    if (t < 10) {
        float av = ba2[t];
        #pragma unroll
        for (int j = 0; j < 64; ++j) av = fmaf(ha[j], Wa2[j * 10 + t], av);
        sA[t] = av;
    }
    if (t == 64) {
        float v = bv2[0];
        #pragma unroll
        for (int j = 0; j < 64; ++j) v = fmaf(hv[j], Wv2[j], v);
        sVM[0] = v;
    }
    __syncthreads();

    if (t == 0) {
        float s = 0.0f;
        #pragma unroll
        for (int j = 0; j < 10; ++j) s += sA[j];
        sVM[1] = s * 0.1f;
    }
    __syncthreads();

    if (t < 10) out[g * 10 + t] = sVM[0] + sA[t] - sVM[1];
}

extern "C" void kernel_launch(void* const* d_in, const int* in_sizes, int n_in,
                              void* d_out, int out_size, void* d_ws, size_t ws_size,
                              hipStream_t stream)
{
    const float* x     = (const float*)d_in[0];
    const float* ea    = (const float*)d_in[1];
    const int*   ei    = (const int*)d_in[2];   // [2*E], row0 = src, row1 = dst
    const int*   batch = (const int*)d_in[3];

    // workspace layout
    float* ws = (float*)d_ws;
    float* xl     = ws;                              // N*128
    float* xr     = xl + (size_t)NN * 128;           // N*128
    float* hA     = xr + (size_t)NN * 128;           // N*128 (layer1 out D=32, layer3 out D=128)
    float* hB     = hA + (size_t)NN * 128;           // N*64  (layer2 out D=64)
    float* pooled = hB + (size_t)NN * 64;            // G*128
    float* cntp   = pooled + (size_t)NG * 128;       // G
    int*   rowptr = (int*)(cntp + NG);               // NN+1
    int*   cnt    = rowptr + (NN + 1);               // NN
    int*   woff   = cnt + NN;                        // NN
    int*   eids   = woff + NN;                       // NE
    int*   esrc   = eids + NE;                       // NE
    float* eaperm = (float*)(esrc + NE);             // NE*FE (optional)

    const size_t need = ((char*)(eaperm + (size_t)NE * FE)) - (char*)d_ws;
    const bool use_perm = (ws_size >= need);

    const int EB = (NE + 255) / 256;

    // ---- CSR by destination (shared across all 3 layers) ----
    hipMemsetAsync(cnt, 0, NN * sizeof(int), stream);
    hipMemsetAsync(woff, 0, NN * sizeof(int), stream);
    k_count<<<dim3(EB), dim3(256), 0, stream>>>(ei, cnt);
    k_scan<<<dim3(1), dim3(1024), 0, stream>>>(cnt, rowptr);
    k_fill<<<dim3(EB), dim3(256), 0, stream>>>(ei, rowptr, woff, eids, esrc);
    if (use_perm) {
        const long long tot = (long long)NE * 4;
        k_gather_ea<<<dim3((unsigned)((tot + 255) / 256)), dim3(256), 0, stream>>>(
            eids, ea, eaperm);
    }

#define LAYER(DIN, DOUT, HIN, HOUT, B)                                                   \
    do {                                                                                 \
        k_node_linear<DIN, DOUT><<<dim3((NN + 15) / 16), dim3(256), 0, stream>>>(        \
            HIN, (const float*)d_in[B], (const float*)d_in[(B) + 1],                     \
            (const float*)d_in[(B) + 2], (const float*)d_in[(B) + 3], xl, xr);           \
        if (use_perm)                                                                    \
            k_gat_fused<DOUT, true><<<dim3(NN), dim3(128), 0, stream>>>(                 \
                rowptr, eids, esrc, eaperm, xl, xr, (const float*)d_in[(B) + 4],         \
                (const float*)d_in[(B) + 5], (const float*)d_in[(B) + 6], HOUT);         \
        else                                                                             \
            k_gat_fused<DOUT, false><<<dim3(NN), dim3(128), 0, stream>>>(                \
                rowptr, eids, esrc, ea, xl, xr, (const float*)d_in[(B) + 4],             \
                (const float*)d_in[(B) + 5], (const float*)d_in[(B) + 6], HOUT);         \
    } while (0)

    LAYER(128, 32, x,  hA, 4);    // layer 1: 128 -> 32
    LAYER(32,  64, hA, hB, 11);   // layer 2: 32  -> 64
    LAYER(64, 128, hB, hA, 18);   // layer 3: 64  -> 128

#undef LAYER

    hipMemsetAsync(pooled, 0, NG * 128 * sizeof(float), stream);
    hipMemsetAsync(cntp, 0, NG * sizeof(float), stream);
    k_pool<<<dim3(512), dim3(128), 0, stream>>>(hA, batch, pooled, cntp);
    k_head<<<dim3(NG), dim3(128), 0, stream>>>(
        pooled, cntp,
        (const float*)d_in[25], (const float*)d_in[26],
        (const float*)d_in[27], (const float*)d_in[28],
        (const float*)d_in[29], (const float*)d_in[30],
        (const float*)d_in[31], (const float*)d_in[32],
        (float*)d_out);
}

// Round 8
// 1000.475 us; speedup vs baseline: 21.4998x; 1.0135x over previous
//
#include <hip/hip_runtime.h>
#include <cstdint>
#include <cstddef>

static constexpr int NN = 50000;     // nodes
static constexpr int NE = 1600000;   // edges
static constexpr int NG = 64;        // graphs
static constexpr int FE = 16;        // edge feature dim
static constexpr float SLOPE = 0.2f; // leaky_relu negative slope

// ---- fused node linear: xl = h@Wl + bl, xr = h@Wr + br ----
template<int DIN, int DOUT>
__global__ __launch_bounds__(256) void k_node_linear(
    const float* __restrict__ h,
    const float* __restrict__ Wl, const float* __restrict__ bl,
    const float* __restrict__ Wr, const float* __restrict__ br,
    float* __restrict__ xl, float* __restrict__ xr)
{
    __shared__ float sW[2 * DIN * DOUT];
    __shared__ float sX[16 * DIN];
    const int n0 = blockIdx.x * 16;

    for (int i = threadIdx.x; i < DIN * DOUT; i += 256) {
        sW[i] = Wl[i];
        sW[DIN * DOUT + i] = Wr[i];
    }
    for (int i = threadIdx.x; i < 16 * DIN; i += 256) {
        int r = i / DIN, k = i % DIN;
        int n = n0 + r;
        sX[i] = (n < NN) ? h[(size_t)n * DIN + k] : 0.0f;
    }
    __syncthreads();

    for (int o = threadIdx.x; o < 16 * DOUT; o += 256) {
        int r = o / DOUT, d = o % DOUT;
        int n = n0 + r;
        if (n >= NN) continue;
        float accl = bl[d], accr = br[d];
        #pragma unroll 8
        for (int k = 0; k < DIN; ++k) {
            float xv = sX[r * DIN + k];
            accl = fmaf(xv, sW[k * DOUT + d], accl);
            accr = fmaf(xv, sW[DIN * DOUT + k * DOUT + d], accr);
        }
        xl[(size_t)n * DOUT + d] = accl;
        xr[(size_t)n * DOUT + d] = accr;
    }
}

// ---- CSR build: count / scan / fill (+ permuted src ids) ----
__global__ __launch_bounds__(256) void k_count(
    const int* __restrict__ ei, int* __restrict__ cnt)
{
    const int e = blockIdx.x * 256 + threadIdx.x;
    if (e >= NE) return;
    atomicAdd(cnt + ei[NE + e], 1);
}

__global__ __launch_bounds__(1024) void k_scan(
    const int* __restrict__ cnt, int* __restrict__ rowptr)
{
    __shared__ int part[1024];
    const int T = 1024;
    const int C = (NN + T - 1) / T;
    const int t = threadIdx.x;
    const int base = t * C;
    int s = 0;
    for (int i = 0; i < C; ++i) {
        int idx = base + i;
        if (idx < NN) s += cnt[idx];
    }
    part[t] = s;
    __syncthreads();
    for (int off = 1; off < T; off <<= 1) {
        int v = 0;
        if (t >= off) v = part[t - off];
        __syncthreads();
        if (t >= off) part[t] += v;
        __syncthreads();
    }
    int run = (t == 0) ? 0 : part[t - 1];
    for (int i = 0; i < C; ++i) {
        int idx = base + i;
        if (idx < NN) { rowptr[idx] = run; run += cnt[idx]; }
    }
    if (t == T - 1) rowptr[NN] = run;
}

__global__ __launch_bounds__(256) void k_fill(
    const int* __restrict__ ei, const int* __restrict__ rowptr,
    int* __restrict__ woff, int* __restrict__ eids, int* __restrict__ esrc)
{
    const int e = blockIdx.x * 256 + threadIdx.x;
    if (e >= NE) return;
    const int dst = ei[NE + e];
    const int pos = rowptr[dst] + atomicAdd(woff + dst, 1);
    eids[pos] = e;
    esrc[pos] = ei[e];
}

// ---- one-time CSR-order gather of edge features (coalesced writes) ----
__global__ __launch_bounds__(256) void k_gather_ea(
    const int* __restrict__ eids, const float* __restrict__ ea,
    float* __restrict__ eap)
{
    const long long i = (long long)blockIdx.x * 256 + threadIdx.x;  // p*4 + q
    if (i >= (long long)NE * 4) return;
    const int p = (int)(i >> 2), q = (int)(i & 3);
    const int e = eids[p];
    *(float4*)(eap + (size_t)p * FE + q * 4) =
        *(const float4*)(ea + (size_t)e * FE + q * 4);
}

// ---- fused GATv2: score + online softmax + aggregate + bias + relu ----
// ONE NODE PER WAVE (2 nodes / 128-thread block). Lane owns dims {2dl, 2dl+1}
// -> all row accesses are float2 vector loads. Stream width SW = D/2 lanes;
// EPW = 64/SW independent edge streams per wave. Zero LDS, zero syncthreads:
// stream merge is a shfl_xor cascade. ea broadcast: scalar s_loads for SW=64
// (wave-uniform row), per-lane float4 loads (same-address broadcast) for
// sub-wave streams — NO ds_bpermute chains (R7's layer-2 bottleneck).
template<int D, bool PERM>
__global__ __launch_bounds__(128, 4) void k_gat_fused(
    const int* __restrict__ rowptr, const int* __restrict__ eidx,
    const int* __restrict__ esrc, const float* __restrict__ eaf,
    const float* __restrict__ xl, const float* __restrict__ xr,
    const float* __restrict__ We, const float* __restrict__ att,
    const float* __restrict__ bo, float* __restrict__ hout)
{
    constexpr int SW  = D / 2;     // stream width in lanes
    constexpr int EPW = 64 / SW;   // edge streams per wave
    constexpr int WPB = 2;         // waves (=nodes) per block

    const int wave = threadIdx.x >> 6;
    const int lane = threadIdx.x & 63;
    const int n = blockIdx.x * WPB + wave;
    if (n >= NN) return;
    const int sub = lane / SW;
    const int dl  = lane % SW;
    const int d0  = 2 * dl;        // owned dims {d0, d0+1}

    // register-resident weights / per-node dest transform
    float rWe[2 * FE], rAtt[2], rXr[2], acc[2];
    {
        const float2 a2 = *(const float2*)(att + d0);
        rAtt[0] = a2.x; rAtt[1] = a2.y;
        const float2 x2 = *(const float2*)(xr + (size_t)n * D + d0);
        rXr[0] = x2.x; rXr[1] = x2.y;
        #pragma unroll
        for (int k = 0; k < FE; ++k) {
            const float2 w2 = *(const float2*)(We + k * D + d0);
            rWe[2 * k] = w2.x; rWe[2 * k + 1] = w2.y;
        }
        acc[0] = acc[1] = 0.f;
    }

    const int p0 = rowptr[n], p1 = rowptr[n + 1];
    float m = -3.4e38f, l = 0.f;

    auto load_edge = [&](int p, float (&eav)[FE], float (&rXl)[2]) {
        const int s = esrc[p];
        const float2 x2 = *(const float2*)(xl + (size_t)s * D + d0);
        rXl[0] = x2.x; rXl[1] = x2.y;
        int erow; if constexpr (PERM) erow = p; else erow = eidx[p];
        if constexpr (SW == 64) {
            // row index wave-uniform; force SGPR base -> scalar loads
            const float* ep = eaf + (size_t)(unsigned)__builtin_amdgcn_readfirstlane(erow) * FE;
            #pragma unroll
            for (int k = 0; k < FE; ++k) eav[k] = ep[k];
        } else {
            // same address across the stream's lanes -> broadcast fetch
            const float* ep = eaf + (size_t)erow * FE;
            #pragma unroll
            for (int k4 = 0; k4 < 4; ++k4) {
                const float4 v = *(const float4*)(ep + 4 * k4);
                eav[4 * k4]     = v.x; eav[4 * k4 + 1] = v.y;
                eav[4 * k4 + 2] = v.z; eav[4 * k4 + 3] = v.w;
            }
        }
    };
    auto score_edge = [&](const float (&eav)[FE], const float (&rXl)[2]) -> float {
        float m0 = rXl[0] + rXr[0], m1 = rXl[1] + rXr[1];
        #pragma unroll
        for (int k = 0; k < FE; ++k) {
            m0 = fmaf(eav[k], rWe[2 * k], m0);
            m1 = fmaf(eav[k], rWe[2 * k + 1], m1);
        }
        m0 = m0 > 0.f ? m0 : SLOPE * m0;
        m1 = m1 > 0.f ? m1 : SLOPE * m1;
        float sv = fmaf(m0, rAtt[0], m1 * rAtt[1]);
        #pragma unroll
        for (int off = 1; off < SW; off <<= 1) sv += __shfl_xor(sv, off);
        return sv;
    };
    auto sm_update = [&](float sv, const float (&rXl)[2]) {
        const float dd = sv - m;
        float wexp;
        if (__builtin_expect(dd > 8.f, 0)) {
            // rare: max grew by >8 -> rescale (exp(-dd)=0 handles first edge)
            const float r = __expf(-dd);
            acc[0] *= r; acc[1] *= r;
            l *= r; m = sv; wexp = 1.f;
        } else {
            wexp = __expf(dd);   // bounded by e^8
        }
        acc[0] = fmaf(wexp, rXl[0], acc[0]);
        acc[1] = fmaf(wexp, rXl[1], acc[1]);
        l += wexp;
    };

    int p = p0 + sub;
    for (; p + EPW < p1; p += 2 * EPW) {
        float eavA[FE], rXlA[2], eavB[FE], rXlB[2];
        load_edge(p, eavA, rXlA);
        load_edge(p + EPW, eavB, rXlB);
        const float svA = score_edge(eavA, rXlA);
        const float svB = score_edge(eavB, rXlB);
        sm_update(svA, rXlA);
        sm_update(svB, rXlB);
    }
    if (p < p1) {
        float eav[FE], rXl[2];
        load_edge(p, eav, rXl);
        sm_update(score_edge(eav, rXl), rXl);
    }

    // ---- merge the EPW streams via shfl_xor cascade (no LDS, no sync) ----
    #pragma unroll
    for (int step = SW; step < 64; step <<= 1) {
        const float mo = __shfl_xor(m, step);
        const float mstar = fmaxf(m, mo);
        const float sc = __expf(m - mstar);   // ==1 when m==mstar (incl. empty)
        acc[0] *= sc; acc[1] *= sc; l *= sc;
        acc[0] += __shfl_xor(acc[0], step);
        acc[1] += __shfl_xor(acc[1], step);
        l += __shfl_xor(l, step);
        m = mstar;
    }

    if (lane < SW) {
        const float inv = 1.0f / (l + 1e-16f);
        const float2 b2 = *(const float2*)(bo + d0);
        float2 o;
        o.x = fmaxf(fmaf(acc[0], inv, b2.x), 0.f);
        o.y = fmaxf(fmaf(acc[1], inv, b2.y), 0.f);
        *(float2*)(hout + (size_t)n * D + d0) = o;
    }
}

// ---- global mean pool: run-length reduction over sorted batch ----
__global__ __launch_bounds__(128) void k_pool(
    const float* __restrict__ h, const int* __restrict__ batch,
    float* __restrict__ pooled, float* __restrict__ cnt)
{
    constexpr int BLOCKS = 512;
    constexpr int CH = (NN + BLOCKS - 1) / BLOCKS;
    const int t = threadIdx.x;
    const int n0 = blockIdx.x * CH;
    const int n1 = min(NN, n0 + CH);
    if (n0 >= n1) return;

    int g = batch[n0];
    float acc = 0.f, c = 0.f;
    for (int n = n0; n < n1; ++n) {
        const int bg = batch[n];
        if (bg != g) {
            atomicAdd(pooled + g * 128 + t, acc);
            if (t == 0) atomicAdd(cnt + g, c);
            acc = 0.f; c = 0.f; g = bg;
        }
        acc += h[(size_t)n * 128 + t];
        c += 1.f;
    }
    atomicAdd(pooled + g * 128 + t, acc);
    if (t == 0) atomicAdd(cnt + g, c);
}

// ---- dueling heads ----
__global__ __launch_bounds__(128) void k_head(
    const float* __restrict__ pooled, const float* __restrict__ cnt,
    const float* __restrict__ Wv1, const float* __restrict__ bv1,
    const float* __restrict__ Wv2, const float* __restrict__ bv2,
    const float* __restrict__ Wa1, const float* __restrict__ ba1,
    const float* __restrict__ Wa2, const float* __restrict__ ba2,
    float* __restrict__ out)
{
    __shared__ float pr[128];
    __shared__ float hv[64];
    __shared__ float ha[64];
    __shared__ float sA[10];
    __shared__ float sVM[2];
    const int g = blockIdx.x;
    const int t = threadIdx.x;

    const float inv = 1.0f / fmaxf(cnt[g], 1.0f);
    pr[t] = pooled[g * 128 + t] * inv;
    __syncthreads();

    if (t < 64) {
        float sv = bv1[t], sa = ba1[t];
        #pragma unroll 8
        for (int k = 0; k < 128; ++k) {
            float p = pr[k];
            sv = fmaf(p, Wv1[k * 64 + t], sv);
            sa = fmaf(p, Wa1[k * 64 + t], sa);
        }
        hv[t] = fmaxf(sv, 0.0f);
        ha[t] = fmaxf(sa, 0.0f);
    }
    __syncthreads();

    if (t < 10) {
        float av = ba2[t];
        #pragma unroll
        for (int j = 0; j < 64; ++j) av = fmaf(ha[j], Wa2[j * 10 + t], av);
        sA[t] = av;
    }
    if (t == 64) {
        float v = bv2[0];
        #pragma unroll
        for (int j = 0; j < 64; ++j) v = fmaf(hv[j], Wv2[j], v);
        sVM[0] = v;
    }
    __syncthreads();

    if (t == 0) {
        float s = 0.0f;
        #pragma unroll
        for (int j = 0; j < 10; ++j) s += sA[j];
        sVM[1] = s * 0.1f;
    }
    __syncthreads();

    if (t < 10) out[g * 10 + t] = sVM[0] + sA[t] - sVM[1];
}

extern "C" void kernel_launch(void* const* d_in, const int* in_sizes, int n_in,
                              void* d_out, int out_size, void* d_ws, size_t ws_size,
                              hipStream_t stream)
{
    const float* x     = (const float*)d_in[0];
    const float* ea    = (const float*)d_in[1];
    const int*   ei    = (const int*)d_in[2];   // [2*E], row0 = src, row1 = dst
    const int*   batch = (const int*)d_in[3];

    // workspace layout
    float* ws = (float*)d_ws;
    float* xl     = ws;                              // N*128
    float* xr     = xl + (size_t)NN * 128;           // N*128
    float* hA     = xr + (size_t)NN * 128;           // N*128 (layer1 out D=32, layer3 out D=128)
    float* hB     = hA + (size_t)NN * 128;           // N*64  (layer2 out D=64)
    float* pooled = hB + (size_t)NN * 64;            // G*128
    float* cntp   = pooled + (size_t)NG * 128;       // G
    int*   rowptr = (int*)(cntp + NG);               // NN+1
    int*   cnt    = rowptr + (NN + 1);               // NN
    int*   woff   = cnt + NN;                        // NN
    int*   eids   = woff + NN;                       // NE
    int*   esrc   = eids + NE;                       // NE
    float* eaperm = (float*)(esrc + NE);             // NE*FE (optional)

    const size_t need = ((char*)(eaperm + (size_t)NE * FE)) - (char*)d_ws;
    const bool use_perm = (ws_size >= need);

    const int EB = (NE + 255) / 256;

    // ---- CSR by destination (shared across all 3 layers) ----
    hipMemsetAsync(cnt, 0, NN * sizeof(int), stream);
    hipMemsetAsync(woff, 0, NN * sizeof(int), stream);
    k_count<<<dim3(EB), dim3(256), 0, stream>>>(ei, cnt);
    k_scan<<<dim3(1), dim3(1024), 0, stream>>>(cnt, rowptr);
    k_fill<<<dim3(EB), dim3(256), 0, stream>>>(ei, rowptr, woff, eids, esrc);
    if (use_perm) {
        const long long tot = (long long)NE * 4;
        k_gather_ea<<<dim3((unsigned)((tot + 255) / 256)), dim3(256), 0, stream>>>(
            eids, ea, eaperm);
    }

    const int GB = (NN + 1) / 2;   // 2 nodes per block (1 per wave)

#define LAYER(DIN, DOUT, HIN, HOUT, B)                                                   \
    do {                                                                                 \
        k_node_linear<DIN, DOUT><<<dim3((NN + 15) / 16), dim3(256), 0, stream>>>(        \
            HIN, (const float*)d_in[B], (const float*)d_in[(B) + 1],                     \
            (const float*)d_in[(B) + 2], (const float*)d_in[(B) + 3], xl, xr);           \
        if (use_perm)                                                                    \
            k_gat_fused<DOUT, true><<<dim3(GB), dim3(128), 0, stream>>>(                 \
                rowptr, eids, esrc, eaperm, xl, xr, (const float*)d_in[(B) + 4],         \
                (const float*)d_in[(B) + 5], (const float*)d_in[(B) + 6], HOUT);         \
        else                                                                             \
            k_gat_fused<DOUT, false><<<dim3(GB), dim3(128), 0, stream>>>(                \
                rowptr, eids, esrc, ea, xl, xr, (const float*)d_in[(B) + 4],             \
                (const float*)d_in[(B) + 5], (const float*)d_in[(B) + 6], HOUT);         \
    } while (0)

    LAYER(128, 32, x,  hA, 4);    // layer 1: 128 -> 32
    LAYER(32,  64, hA, hB, 11);   // layer 2: 32  -> 64
    LAYER(64, 128, hB, hA, 18);   // layer 3: 64  -> 128

#undef LAYER

    hipMemsetAsync(pooled, 0, NG * 128 * sizeof(float), stream);
    hipMemsetAsync(cntp, 0, NG * sizeof(float), stream);
    k_pool<<<dim3(512), dim3(128), 0, stream>>>(hA, batch, pooled, cntp);
    k_head<<<dim3(NG), dim3(128), 0, stream>>>(
        pooled, cntp,
        (const float*)d_in[25], (const float*)d_in[26],
        (const float*)d_in[27], (const float*)d_in[28],
        (const float*)d_in[29], (const float*)d_in[30],
        (const float*)d_in[31], (const float*)d_in[32],
        (float*)d_out);
}